// Round 1
// baseline (4364.251 us; speedup 1.0000x reference)
//
#include <hip/hip_runtime.h>
#include <cmath>

#define N_NODES    100000
#define N_EDGES    1600000
#define NUM_GRAPHS 64

// ---------------- edge scatter-add (hardware f32 atomics) ----------------
// acc must be pre-initialized with the self term (x). One thread = (edge, 4ch).
template<int LOG2T, int C>
__global__ __launch_bounds__(256) void agg_atomic(
    const float* __restrict__ feat, float* __restrict__ acc,
    const int* __restrict__ src_idx, const int* __restrict__ dst_idx)
{
    int tid = blockIdx.x * blockDim.x + threadIdx.x;
    int e   = tid >> LOG2T;
    int c4  = (tid & ((1 << LOG2T) - 1)) << 2;
    if (e >= N_EDGES) return;
    int s = src_idx[e];
    int d = dst_idx[e];
    const float4 v = *(const float4*)(feat + (size_t)s * C + c4);
    float* p = acc + (size_t)d * C + c4;
    unsafeAtomicAdd(p + 0, v.x);
    unsafeAtomicAdd(p + 1, v.y);
    unsafeAtomicAdd(p + 2, v.z);
    unsafeAtomicAdd(p + 3, v.w);
}

// ---------------- MLP1: h1 = relu(relu(h0@W1+b1)@W2+b2) ----------------
// one wave per row; lane = output channel; weights staged in LDS.
__global__ __launch_bounds__(256) void mlp1_kernel(
    const float* __restrict__ h0,
    const float* __restrict__ W1, const float* __restrict__ b1,
    const float* __restrict__ W2, const float* __restrict__ b2,
    float* __restrict__ h1)
{
    __shared__ float sW1[128 * 64];
    __shared__ float sW2[64 * 64];
    __shared__ float sb1[64], sb2[64];
    __shared__ float srow[4][128];
    __shared__ float st[4][64];

    int tid = threadIdx.x;
    for (int i = tid; i < 128 * 64; i += 256) sW1[i] = W1[i];
    for (int i = tid; i < 64 * 64; i += 256)  sW2[i] = W2[i];
    if (tid < 64) { sb1[tid] = b1[tid]; sb2[tid] = b2[tid]; }
    __syncthreads();

    int wave = tid >> 6, lane = tid & 63;
    for (int base = blockIdx.x * 4; base < N_NODES; base += gridDim.x * 4) {
        int r = base + wave;
        if (r < N_NODES) {
            // stage this wave's row (LDS ops within a wave are in-order)
            float2 v = *(const float2*)(h0 + (size_t)r * 128 + lane * 2);
            *(float2*)&srow[wave][lane * 2] = v;

            float acc = sb1[lane];
            #pragma unroll 8
            for (int k = 0; k < 128; ++k)
                acc = fmaf(srow[wave][k], sW1[k * 64 + lane], acc);
            acc = fmaxf(acc, 0.0f);
            st[wave][lane] = acc;

            float acc2 = sb2[lane];
            #pragma unroll 8
            for (int k = 0; k < 64; ++k)
                acc2 = fmaf(st[wave][k], sW2[k * 64 + lane], acc2);
            acc2 = fmaxf(acc2, 0.0f);
            h1[(size_t)r * 64 + lane] = acc2;
        }
    }
}

// ---------------- MLP2 + fused mean-pool accumulation ----------------
// h3 = relu(h2@W3+b3)@W4+b4 ; pooled[batch[r]] += h3[r]
// each wave owns a contiguous 32-row strip; batch is sorted, so flush
// atomics only on graph-id change.
__global__ __launch_bounds__(256) void mlp2_pool_kernel(
    const float* __restrict__ h2,
    const float* __restrict__ W3, const float* __restrict__ b3,
    const float* __restrict__ W4, const float* __restrict__ b4,
    const int* __restrict__ batch,
    float* __restrict__ pooled /* 64 x 128, pre-zeroed */)
{
    __shared__ float sW3[64 * 64];
    __shared__ float sW4[64 * 128];
    __shared__ float sb3[64];
    __shared__ float sb4[128];
    __shared__ float srow[4][64];
    __shared__ float st[4][64];

    int tid = threadIdx.x;
    for (int i = tid; i < 64 * 64; i += 256)  sW3[i] = W3[i];
    for (int i = tid; i < 64 * 128; i += 256) sW4[i] = W4[i];
    if (tid < 64)  sb3[tid] = b3[tid];
    if (tid < 128) sb4[tid] = b4[tid];
    __syncthreads();

    int wave = tid >> 6, lane = tid & 63;
    const int R = 32;
    int w  = blockIdx.x * 4 + wave;
    int r0 = w * R;
    if (r0 >= N_NODES) return;
    int r1 = min(r0 + R, N_NODES);

    float pA = 0.0f, pB = 0.0f;
    int curg = batch[r0];

    for (int r = r0; r < r1; ++r) {
        int g = batch[r];   // uniform across wave
        if (g != curg) {
            unsafeAtomicAdd(&pooled[curg * 128 + lane], pA);
            unsafeAtomicAdd(&pooled[curg * 128 + 64 + lane], pB);
            pA = 0.0f; pB = 0.0f; curg = g;
        }
        srow[wave][lane] = h2[(size_t)r * 64 + lane];

        float a = sb3[lane];
        #pragma unroll 8
        for (int k = 0; k < 64; ++k)
            a = fmaf(srow[wave][k], sW3[k * 64 + lane], a);
        a = fmaxf(a, 0.0f);
        st[wave][lane] = a;

        float oA = sb4[lane], oB = sb4[lane + 64];
        #pragma unroll 8
        for (int k = 0; k < 64; ++k) {
            float t = st[wave][k];
            oA = fmaf(t, sW4[k * 128 + lane], oA);
            oB = fmaf(t, sW4[k * 128 + 64 + lane], oB);
        }
        pA += oA; pB += oB;
    }
    unsafeAtomicAdd(&pooled[curg * 128 + lane], pA);
    unsafeAtomicAdd(&pooled[curg * 128 + 64 + lane], pB);
}

// ---------------- head: mean, FC, log_softmax ----------------
__global__ void head_kernel(
    const float* __restrict__ pooled, const int* __restrict__ batch,
    const float* __restrict__ Wfc, const float* __restrict__ bfc,
    float* __restrict__ out)
{
    int g = threadIdx.x;
    if (g >= NUM_GRAPHS) return;

    // counts via binary search on sorted batch
    int lo = 0, hi = N_NODES;
    while (lo < hi) { int mid = (lo + hi) >> 1; if (batch[mid] < g) lo = mid + 1; else hi = mid; }
    int beg = lo;
    lo = 0; hi = N_NODES;
    while (lo < hi) { int mid = (lo + hi) >> 1; if (batch[mid] < g + 1) lo = mid + 1; else hi = mid; }
    int cnt = lo - beg;
    float inv = 1.0f / fmaxf((float)cnt, 1.0f);

    float logits[10];
    for (int o = 0; o < 10; ++o) {
        float acc = 0.0f;
        for (int k = 0; k < 128; ++k)
            acc = fmaf(pooled[g * 128 + k], Wfc[k * 10 + o], acc);
        logits[o] = acc * inv + bfc[o];
    }
    float m = -INFINITY;
    for (int o = 0; o < 10; ++o) m = fmaxf(m, logits[o]);
    float s = 0.0f;
    for (int o = 0; o < 10; ++o) s += expf(logits[o] - m);
    float ls = logf(s);
    for (int o = 0; o < 10; ++o) out[g * 10 + o] = logits[o] - m - ls;
}

extern "C" void kernel_launch(void* const* d_in, const int* in_sizes, int n_in,
                              void* d_out, int out_size, void* d_ws, size_t ws_size,
                              hipStream_t stream)
{
    const float* x   = (const float*)d_in[0];
    const int*   ei  = (const int*)d_in[1];
    const int*   src = ei;
    const int*   dst = ei + N_EDGES;
    const int*   batch = (const int*)d_in[2];
    const float* W1 = (const float*)d_in[3];
    const float* b1 = (const float*)d_in[4];
    const float* W2 = (const float*)d_in[5];
    const float* b2 = (const float*)d_in[6];
    const float* W3 = (const float*)d_in[7];
    const float* b3 = (const float*)d_in[8];
    const float* W4 = (const float*)d_in[9];
    const float* b4 = (const float*)d_in[10];
    const float* Wfc = (const float*)d_in[11];
    const float* bfc = (const float*)d_in[12];
    float* out = (float*)d_out;

    char* ws = (char*)d_ws;
    float* h0     = (float*)(ws);                              // 100000*128*4 = 51.2 MB
    float* h1     = (float*)(ws + 51200000);                   // 25.6 MB
    float* h2     = (float*)(ws + 51200000 + 25600000);        // 25.6 MB
    float* pooled = (float*)(ws + 51200000 + 25600000 + 25600000); // 32 KB

    // h0 = x (self term), pooled = 0
    hipMemcpyAsync(h0, x, (size_t)N_NODES * 128 * 4, hipMemcpyDeviceToDevice, stream);
    hipMemsetAsync(pooled, 0, NUM_GRAPHS * 128 * 4, stream);

    // agg1: h0 += scatter(x[src] -> dst), 128 ch
    {
        long long threads = (long long)N_EDGES << 5;
        int blocks = (int)((threads + 255) / 256);
        agg_atomic<5, 128><<<blocks, 256, 0, stream>>>(x, h0, src, dst);
    }

    // MLP1
    mlp1_kernel<<<1024, 256, 0, stream>>>(h0, W1, b1, W2, b2, h1);

    // h2 = h1, then agg2: h2 += scatter(h1[src] -> dst), 64 ch
    hipMemcpyAsync(h2, h1, (size_t)N_NODES * 64 * 4, hipMemcpyDeviceToDevice, stream);
    {
        long long threads = (long long)N_EDGES << 4;
        int blocks = (int)((threads + 255) / 256);
        agg_atomic<4, 64><<<blocks, 256, 0, stream>>>(h1, h2, src, dst);
    }

    // MLP2 + pooled accumulation
    {
        int nwaves = (N_NODES + 31) / 32;
        int blocks = (nwaves + 3) / 4;
        mlp2_pool_kernel<<<blocks, 256, 0, stream>>>(h2, W3, b3, W4, b4, batch, pooled);
    }

    // head
    head_kernel<<<1, 64, 0, stream>>>(pooled, batch, Wfc, bfc, out);
}

// Round 2
// 631.303 us; speedup vs baseline: 6.9131x; 6.9131x over previous
//
#include <hip/hip_runtime.h>
#include <cmath>

#define N_NODES    100000
#define N_EDGES    1600000
#define NUM_GRAPHS 64
#define SCAN_CHUNK 1024
#define N_SBLK     ((N_NODES + SCAN_CHUNK - 1) / SCAN_CHUNK)   // 98

// ================= CSR build =================
__global__ __launch_bounds__(256) void hist_kernel(
    const int* __restrict__ dst, int* __restrict__ deg)
{
    int e = blockIdx.x * 256 + threadIdx.x;
    if (e < N_EDGES) atomicAdd(&deg[dst[e]], 1);
}

// pass1: per-block (1024-elem chunk) sums
__global__ __launch_bounds__(256) void scan_pass1(
    const int* __restrict__ deg, int* __restrict__ bsum)
{
    __shared__ int sh[256];
    int base = blockIdx.x * SCAN_CHUNK;
    int tid = threadIdx.x;
    int s = 0;
    #pragma unroll
    for (int j = 0; j < 4; ++j) {
        int i = base + tid * 4 + j;
        if (i < N_NODES) s += deg[i];
    }
    sh[tid] = s;
    __syncthreads();
    for (int off = 128; off > 0; off >>= 1) {
        if (tid < off) sh[tid] += sh[tid + off];
        __syncthreads();
    }
    if (tid == 0) bsum[blockIdx.x] = sh[0];
}

// pass2: serial exclusive scan of 98 block sums (tiny)
__global__ void scan_pass2(int* __restrict__ bsum)
{
    if (threadIdx.x == 0 && blockIdx.x == 0) {
        int run = 0;
        for (int b = 0; b < N_SBLK; ++b) {
            int t = bsum[b];
            bsum[b] = run;
            run += t;
        }
    }
}

// pass3: exclusive scan within chunk + block offset -> rowptr
__global__ __launch_bounds__(256) void scan_pass3(
    const int* __restrict__ deg, const int* __restrict__ bsum,
    int* __restrict__ rowptr)
{
    __shared__ int sh[256];
    int base = blockIdx.x * SCAN_CHUNK;
    int tid = threadIdx.x;
    int v[4];
    int tsum = 0;
    #pragma unroll
    for (int j = 0; j < 4; ++j) {
        int i = base + tid * 4 + j;
        v[j] = (i < N_NODES) ? deg[i] : 0;
        tsum += v[j];
    }
    sh[tid] = tsum;
    __syncthreads();
    // Hillis-Steele inclusive scan over thread sums
    for (int off = 1; off < 256; off <<= 1) {
        int t = (tid >= off) ? sh[tid - off] : 0;
        __syncthreads();
        sh[tid] += t;
        __syncthreads();
    }
    int excl = sh[tid] - tsum + bsum[blockIdx.x];
    #pragma unroll
    for (int j = 0; j < 4; ++j) {
        int i = base + tid * 4 + j;
        if (i < N_NODES) rowptr[i] = excl;
        excl += v[j];
        if (i == N_NODES - 1) rowptr[N_NODES] = excl;
    }
}

__global__ __launch_bounds__(256) void scatter_kernel(
    const int* __restrict__ src, const int* __restrict__ dst,
    int* __restrict__ cursor, int* __restrict__ esrc)
{
    int e = blockIdx.x * 256 + threadIdx.x;
    if (e < N_EDGES) {
        int d = dst[e];
        int p = atomicAdd(&cursor[d], 1);
        esrc[p] = src[e];
    }
}

// ============== gather aggregation, 64 ch: out[i] = y[i] + sum_j y[esrc[j]] ==============
__global__ __launch_bounds__(256) void agg_gather64(
    const float* __restrict__ y, float* __restrict__ out,
    const int* __restrict__ rowptr, const int* __restrict__ esrc)
{
    int wave = threadIdx.x >> 6, lane = threadIdx.x & 63;
    int node = blockIdx.x * 4 + wave;
    if (node >= N_NODES) return;

    float acc = y[(size_t)node * 64 + lane];
    int beg = rowptr[node], end = rowptr[node + 1];
    int e = beg;
    for (; e + 3 < end; e += 4) {
        int i0 = esrc[e], i1 = esrc[e + 1], i2 = esrc[e + 2], i3 = esrc[e + 3];
        float a0 = y[(size_t)i0 * 64 + lane];
        float a1 = y[(size_t)i1 * 64 + lane];
        float a2 = y[(size_t)i2 * 64 + lane];
        float a3 = y[(size_t)i3 * 64 + lane];
        acc += a0 + a1 + a2 + a3;
    }
    for (; e < end; ++e)
        acc += y[(size_t)esrc[e] * 64 + lane];
    out[(size_t)node * 64 + lane] = acc;
}

// ================= GEMM-ish per-row kernels =================
// y = x @ W1   (128 -> 64, no bias)
__global__ __launch_bounds__(256) void k1_gemm(
    const float* __restrict__ x, const float* __restrict__ W1,
    float* __restrict__ y)
{
    __shared__ float sW1[128 * 64];
    __shared__ float srow[4][128];
    int tid = threadIdx.x;
    for (int i = tid; i < 128 * 64; i += 256) sW1[i] = W1[i];
    __syncthreads();

    int wave = tid >> 6, lane = tid & 63;
    for (int base = blockIdx.x * 4; base < N_NODES; base += gridDim.x * 4) {
        int r = base + wave;
        if (r < N_NODES) {
            float2 v = *(const float2*)(x + (size_t)r * 128 + lane * 2);
            *(float2*)&srow[wave][lane * 2] = v;
            float acc = 0.0f;
            #pragma unroll 8
            for (int k = 0; k < 128; ++k)
                acc = fmaf(srow[wave][k], sW1[k * 64 + lane], acc);
            y[(size_t)r * 64 + lane] = acc;
        }
    }
}

// h1 = relu( relu(yagg + b1) @ W2 + b2 )
__global__ __launch_bounds__(256) void k2_kernel(
    const float* __restrict__ yagg,
    const float* __restrict__ b1, const float* __restrict__ W2,
    const float* __restrict__ b2, float* __restrict__ h1)
{
    __shared__ float sW2[64 * 64];
    __shared__ float sb1[64], sb2[64];
    __shared__ float st[4][64];
    int tid = threadIdx.x;
    for (int i = tid; i < 64 * 64; i += 256) sW2[i] = W2[i];
    if (tid < 64) { sb1[tid] = b1[tid]; sb2[tid] = b2[tid]; }
    __syncthreads();

    int wave = tid >> 6, lane = tid & 63;
    for (int base = blockIdx.x * 4; base < N_NODES; base += gridDim.x * 4) {
        int r = base + wave;
        if (r < N_NODES) {
            float t = fmaxf(yagg[(size_t)r * 64 + lane] + sb1[lane], 0.0f);
            st[wave][lane] = t;
            float acc = sb2[lane];
            #pragma unroll 8
            for (int k = 0; k < 64; ++k)
                acc = fmaf(st[wave][k], sW2[k * 64 + lane], acc);
            h1[(size_t)r * 64 + lane] = fmaxf(acc, 0.0f);
        }
    }
}

// z = h1 @ W3   (64 -> 64, no bias)
__global__ __launch_bounds__(256) void k3_gemm(
    const float* __restrict__ h1, const float* __restrict__ W3,
    float* __restrict__ z)
{
    __shared__ float sW3[64 * 64];
    __shared__ float srow[4][64];
    int tid = threadIdx.x;
    for (int i = tid; i < 64 * 64; i += 256) sW3[i] = W3[i];
    __syncthreads();

    int wave = tid >> 6, lane = tid & 63;
    for (int base = blockIdx.x * 4; base < N_NODES; base += gridDim.x * 4) {
        int r = base + wave;
        if (r < N_NODES) {
            srow[wave][lane] = h1[(size_t)r * 64 + lane];
            float acc = 0.0f;
            #pragma unroll 8
            for (int k = 0; k < 64; ++k)
                acc = fmaf(srow[wave][k], sW3[k * 64 + lane], acc);
            z[(size_t)r * 64 + lane] = acc;
        }
    }
}

// o = relu(zagg + b3) @ W4 + b4 ; pooled[batch[r]] += o  (32-row strips, sorted batch)
__global__ __launch_bounds__(256) void k4_pool_kernel(
    const float* __restrict__ zagg,
    const float* __restrict__ b3, const float* __restrict__ W4,
    const float* __restrict__ b4, const int* __restrict__ batch,
    float* __restrict__ pooled)
{
    __shared__ float sW4[64 * 128];
    __shared__ float sb3[64];
    __shared__ float sb4[128];
    __shared__ float st[4][64];
    int tid = threadIdx.x;
    for (int i = tid; i < 64 * 128; i += 256) sW4[i] = W4[i];
    if (tid < 64)  sb3[tid] = b3[tid];
    if (tid < 128) sb4[tid] = b4[tid];
    __syncthreads();

    int wave = tid >> 6, lane = tid & 63;
    const int R = 32;
    int w = blockIdx.x * 4 + wave;
    int r0 = w * R;
    if (r0 >= N_NODES) return;
    int r1 = min(r0 + R, N_NODES);

    float pA = 0.0f, pB = 0.0f;
    int curg = batch[r0];

    for (int r = r0; r < r1; ++r) {
        int g = batch[r];
        if (g != curg) {
            unsafeAtomicAdd(&pooled[curg * 128 + lane], pA);
            unsafeAtomicAdd(&pooled[curg * 128 + 64 + lane], pB);
            pA = 0.0f; pB = 0.0f; curg = g;
        }
        float t = fmaxf(zagg[(size_t)r * 64 + lane] + sb3[lane], 0.0f);
        st[wave][lane] = t;
        float oA = sb4[lane], oB = sb4[lane + 64];
        #pragma unroll 8
        for (int k = 0; k < 64; ++k) {
            float tk = st[wave][k];
            oA = fmaf(tk, sW4[k * 128 + lane], oA);
            oB = fmaf(tk, sW4[k * 128 + 64 + lane], oB);
        }
        pA += oA; pB += oB;
    }
    unsafeAtomicAdd(&pooled[curg * 128 + lane], pA);
    unsafeAtomicAdd(&pooled[curg * 128 + 64 + lane], pB);
}

// ================= head =================
__global__ void head_kernel(
    const float* __restrict__ pooled, const int* __restrict__ batch,
    const float* __restrict__ Wfc, const float* __restrict__ bfc,
    float* __restrict__ out)
{
    int g = threadIdx.x;
    if (g >= NUM_GRAPHS) return;

    int lo = 0, hi = N_NODES;
    while (lo < hi) { int mid = (lo + hi) >> 1; if (batch[mid] < g) lo = mid + 1; else hi = mid; }
    int beg = lo;
    lo = 0; hi = N_NODES;
    while (lo < hi) { int mid = (lo + hi) >> 1; if (batch[mid] < g + 1) lo = mid + 1; else hi = mid; }
    int cnt = lo - beg;
    float inv = 1.0f / fmaxf((float)cnt, 1.0f);

    float logits[10];
    for (int o = 0; o < 10; ++o) {
        float acc = 0.0f;
        for (int k = 0; k < 128; ++k)
            acc = fmaf(pooled[g * 128 + k], Wfc[k * 10 + o], acc);
        logits[o] = acc * inv + bfc[o];
    }
    float m = -INFINITY;
    for (int o = 0; o < 10; ++o) m = fmaxf(m, logits[o]);
    float s = 0.0f;
    for (int o = 0; o < 10; ++o) s += expf(logits[o] - m);
    float ls = logf(s);
    for (int o = 0; o < 10; ++o) out[g * 10 + o] = logits[o] - m - ls;
}

extern "C" void kernel_launch(void* const* d_in, const int* in_sizes, int n_in,
                              void* d_out, int out_size, void* d_ws, size_t ws_size,
                              hipStream_t stream)
{
    const float* x     = (const float*)d_in[0];
    const int*   ei    = (const int*)d_in[1];
    const int*   src   = ei;
    const int*   dst   = ei + N_EDGES;
    const int*   batch = (const int*)d_in[2];
    const float* W1  = (const float*)d_in[3];
    const float* b1  = (const float*)d_in[4];
    const float* W2  = (const float*)d_in[5];
    const float* b2  = (const float*)d_in[6];
    const float* W3  = (const float*)d_in[7];
    const float* b3  = (const float*)d_in[8];
    const float* W4  = (const float*)d_in[9];
    const float* b4  = (const float*)d_in[10];
    const float* Wfc = (const float*)d_in[11];
    const float* bfc = (const float*)d_in[12];
    float* out = (float*)d_out;

    char* ws = (char*)d_ws;
    float* bufA   = (float*)(ws);                      // 25.6 MB
    float* bufB   = (float*)(ws + 25600000);           // 25.6 MB
    int*   esrc   = (int*)  (ws + 51200000);           // 6.4 MB
    int*   rowptr = (int*)  (ws + 57600000);           // 400004 B
    int*   cursor = (int*)  (ws + 58000016);           // 400000 B
    int*   deg    = (int*)  (ws + 58400032);           // 400000 B
    int*   bsum   = (int*)  (ws + 58800032);           // 512 B
    float* pooled = (float*)(ws + 58800544);           // 32 KB

    // ---- CSR build (by dst) ----
    hipMemsetAsync(deg, 0, N_NODES * 4, stream);
    hipMemsetAsync(pooled, 0, NUM_GRAPHS * 128 * 4, stream);
    hist_kernel<<<(N_EDGES + 255) / 256, 256, 0, stream>>>(dst, deg);
    scan_pass1<<<N_SBLK, 256, 0, stream>>>(deg, bsum);
    scan_pass2<<<1, 64, 0, stream>>>(bsum);
    scan_pass3<<<N_SBLK, 256, 0, stream>>>(deg, bsum, rowptr);
    hipMemcpyAsync(cursor, rowptr, N_NODES * 4, hipMemcpyDeviceToDevice, stream);
    scatter_kernel<<<(N_EDGES + 255) / 256, 256, 0, stream>>>(src, dst, cursor, esrc);

    // ---- layer 1: y = x@W1 ; yagg = y + Ay ; h1 = relu(relu(yagg+b1)@W2+b2) ----
    k1_gemm<<<1024, 256, 0, stream>>>(x, W1, bufA);                       // y = bufA
    agg_gather64<<<(N_NODES + 3) / 4, 256, 0, stream>>>(bufA, bufB, rowptr, esrc); // yagg = bufB
    k2_kernel<<<1024, 256, 0, stream>>>(bufB, b1, W2, b2, bufA);          // h1 = bufA

    // ---- layer 2: z = h1@W3 ; zagg = z + Az ; fused MLP2+pool ----
    k3_gemm<<<1024, 256, 0, stream>>>(bufA, W3, bufB);                    // z = bufB
    agg_gather64<<<(N_NODES + 3) / 4, 256, 0, stream>>>(bufB, bufA, rowptr, esrc); // zagg = bufA
    {
        int nwaves = (N_NODES + 31) / 32;
        int blocks = (nwaves + 3) / 4;
        k4_pool_kernel<<<blocks, 256, 0, stream>>>(bufA, b3, W4, b4, batch, pooled);
    }

    head_kernel<<<1, 64, 0, stream>>>(pooled, batch, Wfc, bfc, out);
}

// Round 3
// 436.838 us; speedup vs baseline: 9.9906x; 1.4452x over previous
//
#include <hip/hip_runtime.h>
#include <cmath>

#define N_NODES    100000
#define N_EDGES    1600000
#define NUM_GRAPHS 64
#define SCAN_CHUNK 1024
#define N_SBLK     ((N_NODES + SCAN_CHUNK - 1) / SCAN_CHUNK)   // 98

typedef __attribute__((ext_vector_type(8))) short bf16x8;
typedef __attribute__((ext_vector_type(4))) float f32x4;

__device__ __forceinline__ ushort f2bf(float x) {
    union { float f; uint u; } v; v.f = x;
    uint r = v.u + 0x7fffu + ((v.u >> 16) & 1u);
    return (ushort)(r >> 16);
}
__device__ __forceinline__ float bf2f(ushort u) {
    union { uint u; float f; } v; v.u = ((uint)u) << 16;
    return v.f;
}

// ================= CSR build =================
// rank[e] = position of edge e within its dst bucket (coalesced write)
__global__ __launch_bounds__(256) void hist_rank_kernel(
    const int* __restrict__ dst, int* __restrict__ deg, int* __restrict__ rank)
{
    int e = blockIdx.x * 256 + threadIdx.x;
    if (e < N_EDGES) rank[e] = atomicAdd(&deg[dst[e]], 1);
}

__global__ __launch_bounds__(256) void scan_pass1(
    const int* __restrict__ deg, int* __restrict__ bsum)
{
    __shared__ int sh[256];
    int base = blockIdx.x * SCAN_CHUNK;
    int tid = threadIdx.x;
    int s = 0;
    #pragma unroll
    for (int j = 0; j < 4; ++j) {
        int i = base + tid * 4 + j;
        if (i < N_NODES) s += deg[i];
    }
    sh[tid] = s;
    __syncthreads();
    for (int off = 128; off > 0; off >>= 1) {
        if (tid < off) sh[tid] += sh[tid + off];
        __syncthreads();
    }
    if (tid == 0) bsum[blockIdx.x] = sh[0];
}

// exclusive scan of 98 block sums with one wave (shfl scan)
__global__ void scan_pass2(int* __restrict__ bsum)
{
    int l = threadIdx.x;  // 64 threads
    int va = (l < N_SBLK) ? bsum[l] : 0;
    int a = va;
    #pragma unroll
    for (int off = 1; off < 64; off <<= 1) {
        int t = __shfl_up(a, off, 64);
        if (l >= off) a += t;
    }
    int tot0 = __shfl(a, 63, 64);
    int i2 = 64 + l;
    int vb = (i2 < N_SBLK) ? bsum[i2] : 0;
    int b = vb;
    #pragma unroll
    for (int off = 1; off < 64; off <<= 1) {
        int t = __shfl_up(b, off, 64);
        if (l >= off) b += t;
    }
    if (l < N_SBLK)  bsum[l]  = a - va;
    if (i2 < N_SBLK) bsum[i2] = tot0 + b - vb;
}

__global__ __launch_bounds__(256) void scan_pass3(
    const int* __restrict__ deg, const int* __restrict__ bsum,
    int* __restrict__ rowptr)
{
    __shared__ int sh[256];
    int base = blockIdx.x * SCAN_CHUNK;
    int tid = threadIdx.x;
    int v[4];
    int tsum = 0;
    #pragma unroll
    for (int j = 0; j < 4; ++j) {
        int i = base + tid * 4 + j;
        v[j] = (i < N_NODES) ? deg[i] : 0;
        tsum += v[j];
    }
    sh[tid] = tsum;
    __syncthreads();
    for (int off = 1; off < 256; off <<= 1) {
        int t = (tid >= off) ? sh[tid - off] : 0;
        __syncthreads();
        sh[tid] += t;
        __syncthreads();
    }
    int excl = sh[tid] - tsum + bsum[blockIdx.x];
    #pragma unroll
    for (int j = 0; j < 4; ++j) {
        int i = base + tid * 4 + j;
        if (i < N_NODES) rowptr[i] = excl;
        excl += v[j];
        if (i == N_NODES - 1) rowptr[N_NODES] = excl;
    }
}

// no atomic: slot = rowptr[dst] + rank
__global__ __launch_bounds__(256) void place_kernel(
    const int* __restrict__ src, const int* __restrict__ dst,
    const int* __restrict__ rank, const int* __restrict__ rowptr,
    int* __restrict__ esrc)
{
    int e = blockIdx.x * 256 + threadIdx.x;
    if (e < N_EDGES) {
        esrc[rowptr[dst[e]] + rank[e]] = src[e];
    }
}

// ================= gemm1: y = x @ W1 (f32 in, bf16 out, MFMA) =================
__global__ __launch_bounds__(256) void gemm1_mfma(
    const float* __restrict__ x, const float* __restrict__ W1,
    ushort* __restrict__ y)
{
    int lane = threadIdx.x & 63, wave = threadIdx.x >> 6;
    int lg = lane >> 4, lm = lane & 15;

    // B fragments: Bf[kc][cb], k = kc*32 + lg*8 + i, col = cb*16 + lm
    bf16x8 Bf[4][4];
    #pragma unroll
    for (int kc = 0; kc < 4; ++kc)
        #pragma unroll
        for (int cb = 0; cb < 4; ++cb) {
            bf16x8 t;
            #pragma unroll
            for (int i = 0; i < 8; ++i)
                t[i] = (short)f2bf(W1[(kc * 32 + lg * 8 + i) * 64 + cb * 16 + lm]);
            Bf[kc][cb] = t;
        }

    const int ntiles = N_NODES / 16;   // 6250
    int tile = blockIdx.x * 4 + wave;
    if (tile >= ntiles) return;

    int r = tile * 16 + lm;
    f32x4 acc[4] = {};
    #pragma unroll
    for (int kc = 0; kc < 4; ++kc) {
        const float* p = x + (size_t)r * 128 + kc * 32 + lg * 8;
        float4 a0 = *(const float4*)p;
        float4 a1 = *(const float4*)(p + 4);
        bf16x8 af;
        af[0] = (short)f2bf(a0.x); af[1] = (short)f2bf(a0.y);
        af[2] = (short)f2bf(a0.z); af[3] = (short)f2bf(a0.w);
        af[4] = (short)f2bf(a1.x); af[5] = (short)f2bf(a1.y);
        af[6] = (short)f2bf(a1.z); af[7] = (short)f2bf(a1.w);
        #pragma unroll
        for (int cb = 0; cb < 4; ++cb)
            acc[cb] = __builtin_amdgcn_mfma_f32_16x16x32_bf16(af, Bf[kc][cb], acc[cb], 0, 0, 0);
    }
    #pragma unroll
    for (int cb = 0; cb < 4; ++cb)
        #pragma unroll
        for (int i = 0; i < 4; ++i)
            y[(size_t)(tile * 16 + lg * 4 + i) * 64 + cb * 16 + lm] = f2bf(acc[cb][i]);
}

// ============== gather (bf16 in/out, f32 accum): out[i] = in[i] + sum in[esrc] ==============
__global__ __launch_bounds__(256) void agg_bf16(
    const uint* __restrict__ in, uint* __restrict__ out,
    const int* __restrict__ rowptr, const int* __restrict__ esrc)
{
    int wave = threadIdx.x >> 6, lane = threadIdx.x & 63;
    int node = blockIdx.x * 4 + wave;
    if (node >= N_NODES) return;
    int h = lane >> 5, c = lane & 31;

    float alo = 0.0f, ahi = 0.0f;
    if (h == 0) {
        uint self = in[(size_t)node * 32 + c];
        alo = bf2f((ushort)(self & 0xffffu));
        ahi = bf2f((ushort)(self >> 16));
    }
    int beg = rowptr[node], end = rowptr[node + 1];
    for (int e = beg + h; e < end; e += 2) {
        uint v = in[(size_t)esrc[e] * 32 + c];
        alo += bf2f((ushort)(v & 0xffffu));
        ahi += bf2f((ushort)(v >> 16));
    }
    alo += __shfl_xor(alo, 32, 64);
    ahi += __shfl_xor(ahi, 32, 64);
    if (h == 0)
        out[(size_t)node * 32 + c] = (uint)f2bf(alo) | ((uint)f2bf(ahi) << 16);
}

// ===== fused_mid: t=relu(yagg+b1); h1=relu(t@W2+b2); z=h1@W3 (bf16 MFMA) =====
__global__ __launch_bounds__(256) void fused_mid(
    const ushort* __restrict__ yagg, const float* __restrict__ b1,
    const float* __restrict__ W2, const float* __restrict__ b2,
    const float* __restrict__ W3, ushort* __restrict__ z)
{
    __shared__ __align__(16) float trs[4][16 * 68];   // padded transpose buffer, per wave
    int lane = threadIdx.x & 63, wave = threadIdx.x >> 6;
    int lg = lane >> 4, lm = lane & 15;

    bf16x8 B2[2][4], B3[2][4];
    #pragma unroll
    for (int kc = 0; kc < 2; ++kc)
        #pragma unroll
        for (int cb = 0; cb < 4; ++cb) {
            bf16x8 t2, t3;
            #pragma unroll
            for (int i = 0; i < 8; ++i) {
                int k = kc * 32 + lg * 8 + i;
                int cc = cb * 16 + lm;
                t2[i] = (short)f2bf(W2[k * 64 + cc]);
                t3[i] = (short)f2bf(W3[k * 64 + cc]);
            }
            B2[kc][cb] = t2; B3[kc][cb] = t3;
        }
    float b1r[2][8];
    #pragma unroll
    for (int kc = 0; kc < 2; ++kc)
        #pragma unroll
        for (int i = 0; i < 8; ++i)
            b1r[kc][i] = b1[kc * 32 + lg * 8 + i];
    float b2r[4];
    #pragma unroll
    for (int cb = 0; cb < 4; ++cb) b2r[cb] = b2[cb * 16 + lm];

    const int ntiles = N_NODES / 16;
    int tile = blockIdx.x * 4 + wave;
    if (tile >= ntiles) return;

    int r = tile * 16 + lm;
    // A1 = relu(yagg + b1) in fragment layout
    bf16x8 A1[2];
    #pragma unroll
    for (int kc = 0; kc < 2; ++kc) {
        uint4 raw = *(const uint4*)(yagg + (size_t)r * 64 + kc * 32 + lg * 8);
        uint w[4] = {raw.x, raw.y, raw.z, raw.w};
        bf16x8 t;
        #pragma unroll
        for (int j = 0; j < 4; ++j) {
            float flo = bf2f((ushort)(w[j] & 0xffffu)) + b1r[kc][2 * j];
            float fhi = bf2f((ushort)(w[j] >> 16)) + b1r[kc][2 * j + 1];
            t[2 * j]     = (short)f2bf(fmaxf(flo, 0.0f));
            t[2 * j + 1] = (short)f2bf(fmaxf(fhi, 0.0f));
        }
        A1[kc] = t;
    }
    // GEMM2
    f32x4 acc[4] = {};
    #pragma unroll
    for (int kc = 0; kc < 2; ++kc)
        #pragma unroll
        for (int cb = 0; cb < 4; ++cb)
            acc[cb] = __builtin_amdgcn_mfma_f32_16x16x32_bf16(A1[kc], B2[kc][cb], acc[cb], 0, 0, 0);
    // h1 = relu(acc + b2) -> LDS (row stride 68 floats, 16B aligned)
    #pragma unroll
    for (int cb = 0; cb < 4; ++cb)
        #pragma unroll
        for (int i = 0; i < 4; ++i)
            trs[wave][(lg * 4 + i) * 68 + cb * 16 + lm] = fmaxf(acc[cb][i] + b2r[cb], 0.0f);
    // read back transposed as A-fragments (same wave -> no barrier needed)
    bf16x8 A2[2];
    #pragma unroll
    for (int kc = 0; kc < 2; ++kc) {
        const float* p = &trs[wave][lm * 68 + kc * 32 + lg * 8];
        float4 u0 = *(const float4*)p;
        float4 u1 = *(const float4*)(p + 4);
        bf16x8 t;
        t[0] = (short)f2bf(u0.x); t[1] = (short)f2bf(u0.y);
        t[2] = (short)f2bf(u0.z); t[3] = (short)f2bf(u0.w);
        t[4] = (short)f2bf(u1.x); t[5] = (short)f2bf(u1.y);
        t[6] = (short)f2bf(u1.z); t[7] = (short)f2bf(u1.w);
        A2[kc] = t;
    }
    // GEMM3
    f32x4 acc2[4] = {};
    #pragma unroll
    for (int kc = 0; kc < 2; ++kc)
        #pragma unroll
        for (int cb = 0; cb < 4; ++cb)
            acc2[cb] = __builtin_amdgcn_mfma_f32_16x16x32_bf16(A2[kc], B3[kc][cb], acc2[cb], 0, 0, 0);
    #pragma unroll
    for (int cb = 0; cb < 4; ++cb)
        #pragma unroll
        for (int i = 0; i < 4; ++i)
            z[(size_t)(tile * 16 + lg * 4 + i) * 64 + cb * 16 + lm] = f2bf(acc2[cb][i]);
}

// ===== k4: o = relu(zagg+b3)@W4+b4 ; pooled[batch[r]] += o (f32, 32-row strips) =====
__global__ __launch_bounds__(256) void k4_pool_kernel(
    const uint* __restrict__ zin,
    const float* __restrict__ b3, const float* __restrict__ W4,
    const float* __restrict__ b4, const int* __restrict__ batch,
    float* __restrict__ pooled)
{
    __shared__ float sW4[64 * 128];
    __shared__ float sb3[64];
    __shared__ float sb4[128];
    __shared__ float st[4][64];
    __shared__ float srow[4][64];
    int tid = threadIdx.x;
    for (int i = tid; i < 64 * 128; i += 256) sW4[i] = W4[i];
    if (tid < 64)  sb3[tid] = b3[tid];
    if (tid < 128) sb4[tid] = b4[tid];
    __syncthreads();

    int wave = tid >> 6, lane = tid & 63;
    const int R = 32;
    int w = blockIdx.x * 4 + wave;
    int r0 = w * R;
    if (r0 >= N_NODES) return;
    int r1 = min(r0 + R, N_NODES);

    float pA = 0.0f, pB = 0.0f;
    int curg = batch[r0];

    for (int r = r0; r < r1; ++r) {
        int g = batch[r];
        if (g != curg) {
            unsafeAtomicAdd(&pooled[curg * 128 + lane], pA);
            unsafeAtomicAdd(&pooled[curg * 128 + 64 + lane], pB);
            pA = 0.0f; pB = 0.0f; curg = g;
        }
        if (lane < 32) {
            uint v = zin[(size_t)r * 32 + lane];
            srow[wave][lane * 2]     = bf2f((ushort)(v & 0xffffu));
            srow[wave][lane * 2 + 1] = bf2f((ushort)(v >> 16));
        }
        float t = fmaxf(srow[wave][lane] * 0.0f + srow[wave][lane], 0.0f); // placeholder avoided below
        t = fmaxf(srow[wave][lane] + sb3[lane], 0.0f);
        st[wave][lane] = t;
        float oA = sb4[lane], oB = sb4[lane + 64];
        #pragma unroll 8
        for (int k = 0; k < 64; ++k) {
            float tk = st[wave][k];
            oA = fmaf(tk, sW4[k * 128 + lane], oA);
            oB = fmaf(tk, sW4[k * 128 + 64 + lane], oB);
        }
        pA += oA; pB += oB;
    }
    unsafeAtomicAdd(&pooled[curg * 128 + lane], pA);
    unsafeAtomicAdd(&pooled[curg * 128 + 64 + lane], pB);
}

// ================= head =================
__global__ void head_kernel(
    const float* __restrict__ pooled, const int* __restrict__ batch,
    const float* __restrict__ Wfc, const float* __restrict__ bfc,
    float* __restrict__ out)
{
    int g = threadIdx.x;
    if (g >= NUM_GRAPHS) return;

    int lo = 0, hi = N_NODES;
    while (lo < hi) { int mid = (lo + hi) >> 1; if (batch[mid] < g) lo = mid + 1; else hi = mid; }
    int beg = lo;
    lo = 0; hi = N_NODES;
    while (lo < hi) { int mid = (lo + hi) >> 1; if (batch[mid] < g + 1) lo = mid + 1; else hi = mid; }
    int cnt = lo - beg;
    float inv = 1.0f / fmaxf((float)cnt, 1.0f);

    float logits[10];
    for (int o = 0; o < 10; ++o) {
        float acc = 0.0f;
        for (int k = 0; k < 128; ++k)
            acc = fmaf(pooled[g * 128 + k], Wfc[k * 10 + o], acc);
        logits[o] = acc * inv + bfc[o];
    }
    float m = -INFINITY;
    for (int o = 0; o < 10; ++o) m = fmaxf(m, logits[o]);
    float s = 0.0f;
    for (int o = 0; o < 10; ++o) s += expf(logits[o] - m);
    float ls = logf(s);
    for (int o = 0; o < 10; ++o) out[g * 10 + o] = logits[o] - m - ls;
}

extern "C" void kernel_launch(void* const* d_in, const int* in_sizes, int n_in,
                              void* d_out, int out_size, void* d_ws, size_t ws_size,
                              hipStream_t stream)
{
    const float* x     = (const float*)d_in[0];
    const int*   ei    = (const int*)d_in[1];
    const int*   src   = ei;
    const int*   dst   = ei + N_EDGES;
    const int*   batch = (const int*)d_in[2];
    const float* W1  = (const float*)d_in[3];
    const float* b1  = (const float*)d_in[4];
    const float* W2  = (const float*)d_in[5];
    const float* b2  = (const float*)d_in[6];
    const float* W3  = (const float*)d_in[7];
    const float* b3  = (const float*)d_in[8];
    const float* W4  = (const float*)d_in[9];
    const float* b4  = (const float*)d_in[10];
    const float* Wfc = (const float*)d_in[11];
    const float* bfc = (const float*)d_in[12];
    float* out = (float*)d_out;

    char* ws = (char*)d_ws;
    ushort* bufA  = (ushort*)(ws);                 // 12.8 MB  (bf16 node features)
    ushort* bufB  = (ushort*)(ws + 12800000);      // 12.8 MB
    int* esrc     = (int*)(ws + 25600000);         // 6.4 MB
    int* rank     = (int*)(ws + 32000000);         // 6.4 MB
    int* rowptr   = (int*)(ws + 38400000);         // 400004 B
    int* deg      = (int*)(ws + 38800016);         // 400000 B
    int* bsum     = (int*)(ws + 39200016);         // 512 B
    float* pooled = (float*)(ws + 39200528);       // 32 KB

    // ---- CSR build ----
    hipMemsetAsync(deg, 0, N_NODES * 4, stream);
    hipMemsetAsync(pooled, 0, NUM_GRAPHS * 128 * 4, stream);
    hist_rank_kernel<<<(N_EDGES + 255) / 256, 256, 0, stream>>>(dst, deg, rank);
    scan_pass1<<<N_SBLK, 256, 0, stream>>>(deg, bsum);
    scan_pass2<<<1, 64, 0, stream>>>(bsum);
    scan_pass3<<<N_SBLK, 256, 0, stream>>>(deg, bsum, rowptr);
    place_kernel<<<(N_EDGES + 255) / 256, 256, 0, stream>>>(src, dst, rank, rowptr, esrc);

    // ---- layer 1 ----
    gemm1_mfma<<<(N_NODES / 16 + 3) / 4, 256, 0, stream>>>(x, W1, bufA);               // y
    agg_bf16<<<N_NODES / 4, 256, 0, stream>>>((const uint*)bufA, (uint*)bufB, rowptr, esrc); // yagg
    fused_mid<<<(N_NODES / 16 + 3) / 4, 256, 0, stream>>>(bufB, b1, W2, b2, W3, bufA); // z

    // ---- layer 2 ----
    agg_bf16<<<N_NODES / 4, 256, 0, stream>>>((const uint*)bufA, (uint*)bufB, rowptr, esrc); // zagg
    k4_pool_kernel<<<((N_NODES + 31) / 32 + 3) / 4, 256, 0, stream>>>(
        (const uint*)bufB, b3, W4, b4, batch, pooled);

    head_kernel<<<1, 64, 0, stream>>>(pooled, batch, Wfc, bfc, out);
}

// Round 4
// 310.399 us; speedup vs baseline: 14.0601x; 1.4073x over previous
//
#include <hip/hip_runtime.h>
#include <cmath>

#define N_NODES    100000
#define N_EDGES    1600000
#define NUM_GRAPHS 64
#define SCAN_CHUNK 1024
#define N_SBLK     ((N_NODES + SCAN_CHUNK - 1) / SCAN_CHUNK)   // 98

typedef __attribute__((ext_vector_type(8))) short bf16x8;
typedef __attribute__((ext_vector_type(4))) float f32x4;

__device__ __forceinline__ ushort f2bf(float x) {
    union { float f; uint u; } v; v.f = x;
    uint r = v.u + 0x7fffu + ((v.u >> 16) & 1u);
    return (ushort)(r >> 16);
}
__device__ __forceinline__ float bf2f(ushort u) {
    union { uint u; float f; } v; v.u = ((uint)u) << 16;
    return v.f;
}

// ================= CSR build =================
__global__ __launch_bounds__(256) void hist_rank_kernel(
    const int* __restrict__ dst, int* __restrict__ deg, int* __restrict__ rank)
{
    int e = blockIdx.x * 256 + threadIdx.x;
    if (e < N_EDGES) rank[e] = atomicAdd(&deg[dst[e]], 1);
}

__global__ __launch_bounds__(256) void scan_pass1(
    const int* __restrict__ deg, int* __restrict__ bsum)
{
    __shared__ int sh[256];
    int base = blockIdx.x * SCAN_CHUNK;
    int tid = threadIdx.x;
    int s = 0;
    #pragma unroll
    for (int j = 0; j < 4; ++j) {
        int i = base + tid * 4 + j;
        if (i < N_NODES) s += deg[i];
    }
    sh[tid] = s;
    __syncthreads();
    for (int off = 128; off > 0; off >>= 1) {
        if (tid < off) sh[tid] += sh[tid + off];
        __syncthreads();
    }
    if (tid == 0) bsum[blockIdx.x] = sh[0];
}

__global__ void scan_pass2(int* __restrict__ bsum)
{
    int l = threadIdx.x;  // 64 threads
    int va = (l < N_SBLK) ? bsum[l] : 0;
    int a = va;
    #pragma unroll
    for (int off = 1; off < 64; off <<= 1) {
        int t = __shfl_up(a, off, 64);
        if (l >= off) a += t;
    }
    int tot0 = __shfl(a, 63, 64);
    int i2 = 64 + l;
    int vb = (i2 < N_SBLK) ? bsum[i2] : 0;
    int b = vb;
    #pragma unroll
    for (int off = 1; off < 64; off <<= 1) {
        int t = __shfl_up(b, off, 64);
        if (l >= off) b += t;
    }
    if (l < N_SBLK)  bsum[l]  = a - va;
    if (i2 < N_SBLK) bsum[i2] = tot0 + b - vb;
}

__global__ __launch_bounds__(256) void scan_pass3(
    const int* __restrict__ deg, const int* __restrict__ bsum,
    int* __restrict__ rowptr)
{
    __shared__ int sh[256];
    int base = blockIdx.x * SCAN_CHUNK;
    int tid = threadIdx.x;
    int v[4];
    int tsum = 0;
    #pragma unroll
    for (int j = 0; j < 4; ++j) {
        int i = base + tid * 4 + j;
        v[j] = (i < N_NODES) ? deg[i] : 0;
        tsum += v[j];
    }
    sh[tid] = tsum;
    __syncthreads();
    for (int off = 1; off < 256; off <<= 1) {
        int t = (tid >= off) ? sh[tid - off] : 0;
        __syncthreads();
        sh[tid] += t;
        __syncthreads();
    }
    int excl = sh[tid] - tsum + bsum[blockIdx.x];
    #pragma unroll
    for (int j = 0; j < 4; ++j) {
        int i = base + tid * 4 + j;
        if (i < N_NODES) rowptr[i] = excl;
        excl += v[j];
        if (i == N_NODES - 1) rowptr[N_NODES] = excl;
    }
}

__global__ __launch_bounds__(256) void place_kernel(
    const int* __restrict__ src, const int* __restrict__ dst,
    const int* __restrict__ rank, const int* __restrict__ rowptr,
    int* __restrict__ esrc)
{
    int e = blockIdx.x * 256 + threadIdx.x;
    if (e < N_EDGES) {
        esrc[rowptr[dst[e]] + rank[e]] = src[e];
    }
}

// ================= gemm1: y = x @ W1 (f32 in, bf16 out, MFMA) =================
__global__ __launch_bounds__(256) void gemm1_mfma(
    const float* __restrict__ x, const float* __restrict__ W1,
    ushort* __restrict__ y)
{
    int lane = threadIdx.x & 63, wave = threadIdx.x >> 6;
    int lg = lane >> 4, lm = lane & 15;

    bf16x8 Bf[4][4];
    #pragma unroll
    for (int kc = 0; kc < 4; ++kc)
        #pragma unroll
        for (int cb = 0; cb < 4; ++cb) {
            bf16x8 t;
            #pragma unroll
            for (int i = 0; i < 8; ++i)
                t[i] = (short)f2bf(W1[(kc * 32 + lg * 8 + i) * 64 + cb * 16 + lm]);
            Bf[kc][cb] = t;
        }

    const int ntiles = N_NODES / 16;   // 6250
    int tile = blockIdx.x * 4 + wave;
    if (tile >= ntiles) return;

    int r = tile * 16 + lm;
    f32x4 acc[4] = {};
    #pragma unroll
    for (int kc = 0; kc < 4; ++kc) {
        const float* p = x + (size_t)r * 128 + kc * 32 + lg * 8;
        float4 a0 = *(const float4*)p;
        float4 a1 = *(const float4*)(p + 4);
        bf16x8 af;
        af[0] = (short)f2bf(a0.x); af[1] = (short)f2bf(a0.y);
        af[2] = (short)f2bf(a0.z); af[3] = (short)f2bf(a0.w);
        af[4] = (short)f2bf(a1.x); af[5] = (short)f2bf(a1.y);
        af[6] = (short)f2bf(a1.z); af[7] = (short)f2bf(a1.w);
        #pragma unroll
        for (int cb = 0; cb < 4; ++cb)
            acc[cb] = __builtin_amdgcn_mfma_f32_16x16x32_bf16(af, Bf[kc][cb], acc[cb], 0, 0, 0);
    }
    #pragma unroll
    for (int cb = 0; cb < 4; ++cb)
        #pragma unroll
        for (int i = 0; i < 4; ++i)
            y[(size_t)(tile * 16 + lg * 4 + i) * 64 + cb * 16 + lm] = f2bf(acc[cb][i]);
}

// ============== gather (bf16, f32 accum), 2-edge ILP per half-wave ==============
__global__ __launch_bounds__(256) void agg_bf16(
    const uint* __restrict__ in, uint* __restrict__ out,
    const int* __restrict__ rowptr, const int* __restrict__ esrc)
{
    int wave = threadIdx.x >> 6, lane = threadIdx.x & 63;
    int node = blockIdx.x * 4 + wave;
    if (node >= N_NODES) return;
    int h = lane >> 5, c = lane & 31;

    float alo = 0.0f, ahi = 0.0f;
    if (h == 0) {
        uint self = in[(size_t)node * 32 + c];
        alo = bf2f((ushort)(self & 0xffffu));
        ahi = bf2f((ushort)(self >> 16));
    }
    int beg = rowptr[node], end = rowptr[node + 1];
    int e = beg + h;
    // two edges in flight per half-wave (4 per wave)
    for (; e + 2 < end; e += 4) {
        int i0 = esrc[e], i1 = esrc[e + 2];
        uint v0 = in[(size_t)i0 * 32 + c];
        uint v1 = in[(size_t)i1 * 32 + c];
        alo += bf2f((ushort)(v0 & 0xffffu)) + bf2f((ushort)(v1 & 0xffffu));
        ahi += bf2f((ushort)(v0 >> 16))     + bf2f((ushort)(v1 >> 16));
    }
    for (; e < end; e += 2) {
        uint v = in[(size_t)esrc[e] * 32 + c];
        alo += bf2f((ushort)(v & 0xffffu));
        ahi += bf2f((ushort)(v >> 16));
    }
    alo += __shfl_xor(alo, 32, 64);
    ahi += __shfl_xor(ahi, 32, 64);
    if (h == 0)
        out[(size_t)node * 32 + c] = (uint)f2bf(alo) | ((uint)f2bf(ahi) << 16);
}

// ===== fused_mid: t=relu(yagg+b1); h1=relu(t@W2+b2); z=h1@W3 (bf16 MFMA) =====
__global__ __launch_bounds__(256) void fused_mid(
    const ushort* __restrict__ yagg, const float* __restrict__ b1,
    const float* __restrict__ W2, const float* __restrict__ b2,
    const float* __restrict__ W3, ushort* __restrict__ z)
{
    __shared__ __align__(16) float trs[4][16 * 68];
    int lane = threadIdx.x & 63, wave = threadIdx.x >> 6;
    int lg = lane >> 4, lm = lane & 15;

    bf16x8 B2[2][4], B3[2][4];
    #pragma unroll
    for (int kc = 0; kc < 2; ++kc)
        #pragma unroll
        for (int cb = 0; cb < 4; ++cb) {
            bf16x8 t2, t3;
            #pragma unroll
            for (int i = 0; i < 8; ++i) {
                int k = kc * 32 + lg * 8 + i;
                int cc = cb * 16 + lm;
                t2[i] = (short)f2bf(W2[k * 64 + cc]);
                t3[i] = (short)f2bf(W3[k * 64 + cc]);
            }
            B2[kc][cb] = t2; B3[kc][cb] = t3;
        }
    float b1r[2][8];
    #pragma unroll
    for (int kc = 0; kc < 2; ++kc)
        #pragma unroll
        for (int i = 0; i < 8; ++i)
            b1r[kc][i] = b1[kc * 32 + lg * 8 + i];
    float b2r[4];
    #pragma unroll
    for (int cb = 0; cb < 4; ++cb) b2r[cb] = b2[cb * 16 + lm];

    const int ntiles = N_NODES / 16;
    int tile = blockIdx.x * 4 + wave;
    if (tile >= ntiles) return;

    int r = tile * 16 + lm;
    bf16x8 A1[2];
    #pragma unroll
    for (int kc = 0; kc < 2; ++kc) {
        uint4 raw = *(const uint4*)(yagg + (size_t)r * 64 + kc * 32 + lg * 8);
        uint w[4] = {raw.x, raw.y, raw.z, raw.w};
        bf16x8 t;
        #pragma unroll
        for (int j = 0; j < 4; ++j) {
            float flo = bf2f((ushort)(w[j] & 0xffffu)) + b1r[kc][2 * j];
            float fhi = bf2f((ushort)(w[j] >> 16)) + b1r[kc][2 * j + 1];
            t[2 * j]     = (short)f2bf(fmaxf(flo, 0.0f));
            t[2 * j + 1] = (short)f2bf(fmaxf(fhi, 0.0f));
        }
        A1[kc] = t;
    }
    f32x4 acc[4] = {};
    #pragma unroll
    for (int kc = 0; kc < 2; ++kc)
        #pragma unroll
        for (int cb = 0; cb < 4; ++cb)
            acc[cb] = __builtin_amdgcn_mfma_f32_16x16x32_bf16(A1[kc], B2[kc][cb], acc[cb], 0, 0, 0);
    #pragma unroll
    for (int cb = 0; cb < 4; ++cb)
        #pragma unroll
        for (int i = 0; i < 4; ++i)
            trs[wave][(lg * 4 + i) * 68 + cb * 16 + lm] = fmaxf(acc[cb][i] + b2r[cb], 0.0f);
    bf16x8 A2[2];
    #pragma unroll
    for (int kc = 0; kc < 2; ++kc) {
        const float* p = &trs[wave][lm * 68 + kc * 32 + lg * 8];
        float4 u0 = *(const float4*)p;
        float4 u1 = *(const float4*)(p + 4);
        bf16x8 t;
        t[0] = (short)f2bf(u0.x); t[1] = (short)f2bf(u0.y);
        t[2] = (short)f2bf(u0.z); t[3] = (short)f2bf(u0.w);
        t[4] = (short)f2bf(u1.x); t[5] = (short)f2bf(u1.y);
        t[6] = (short)f2bf(u1.z); t[7] = (short)f2bf(u1.w);
        A2[kc] = t;
    }
    f32x4 acc2[4] = {};
    #pragma unroll
    for (int kc = 0; kc < 2; ++kc)
        #pragma unroll
        for (int cb = 0; cb < 4; ++cb)
            acc2[cb] = __builtin_amdgcn_mfma_f32_16x16x32_bf16(A2[kc], B3[kc][cb], acc2[cb], 0, 0, 0);
    #pragma unroll
    for (int cb = 0; cb < 4; ++cb)
        #pragma unroll
        for (int i = 0; i < 4; ++i)
            z[(size_t)(tile * 16 + lg * 4 + i) * 64 + cb * 16 + lm] = f2bf(acc2[cb][i]);
}

// ===== k4 MFMA: o = relu(zagg+b3)@W4+b4 ; pooled[batch[r]] += o =====
// D-layout register pooling: pacc[cb] per lane, flush on graph change via
// shfl-reduce over lg groups + 128 atomics.
__global__ __launch_bounds__(256) void k4_mfma_pool(
    const ushort* __restrict__ zagg, const float* __restrict__ b3,
    const float* __restrict__ W4, const float* __restrict__ b4,
    const int* __restrict__ batch, float* __restrict__ pooled)
{
    int lane = threadIdx.x & 63, wave = threadIdx.x >> 6;
    int lg = lane >> 4, lm = lane & 15;

    bf16x8 B4[2][8];
    #pragma unroll
    for (int kc = 0; kc < 2; ++kc)
        #pragma unroll
        for (int cb = 0; cb < 8; ++cb) {
            bf16x8 t;
            #pragma unroll
            for (int i = 0; i < 8; ++i)
                t[i] = (short)f2bf(W4[(kc * 32 + lg * 8 + i) * 128 + cb * 16 + lm]);
            B4[kc][cb] = t;
        }
    float b3r[2][8];
    #pragma unroll
    for (int kc = 0; kc < 2; ++kc)
        #pragma unroll
        for (int i = 0; i < 8; ++i)
            b3r[kc][i] = b3[kc * 32 + lg * 8 + i];
    float b4r[8];
    #pragma unroll
    for (int cb = 0; cb < 8; ++cb) b4r[cb] = b4[cb * 16 + lm];

    const int NT = N_NODES / 16;   // 6250
    const int TPW = 4;
    int w = blockIdx.x * 4 + wave;
    int t0 = w * TPW;
    if (t0 >= NT) return;
    int t1 = min(t0 + TPW, NT);

    float pacc[8] = {0, 0, 0, 0, 0, 0, 0, 0};
    int curg = batch[t0 * 16];

#define FLUSH(G) do {                                                     \
        _Pragma("unroll")                                                 \
        for (int cb = 0; cb < 8; ++cb) {                                  \
            float v = pacc[cb];                                           \
            v += __shfl_xor(v, 16, 64);                                   \
            v += __shfl_xor(v, 32, 64);                                   \
            if (lane < 16) unsafeAtomicAdd(&pooled[(G) * 128 + cb * 16 + lm], v); \
            pacc[cb] = 0.0f;                                              \
        }                                                                 \
    } while (0)

    for (int t = t0; t < t1; ++t) {
        int rbase = t * 16;
        int r = rbase + lm;
        bf16x8 A[2];
        #pragma unroll
        for (int kc = 0; kc < 2; ++kc) {
            uint4 raw = *(const uint4*)(zagg + (size_t)r * 64 + kc * 32 + lg * 8);
            uint wv[4] = {raw.x, raw.y, raw.z, raw.w};
            bf16x8 tt;
            #pragma unroll
            for (int j = 0; j < 4; ++j) {
                float flo = bf2f((ushort)(wv[j] & 0xffffu)) + b3r[kc][2 * j];
                float fhi = bf2f((ushort)(wv[j] >> 16))    + b3r[kc][2 * j + 1];
                tt[2 * j]     = (short)f2bf(fmaxf(flo, 0.0f));
                tt[2 * j + 1] = (short)f2bf(fmaxf(fhi, 0.0f));
            }
            A[kc] = tt;
        }
        f32x4 acc[8] = {};
        #pragma unroll
        for (int kc = 0; kc < 2; ++kc)
            #pragma unroll
            for (int cb = 0; cb < 8; ++cb)
                acc[cb] = __builtin_amdgcn_mfma_f32_16x16x32_bf16(A[kc], B4[kc][cb], acc[cb], 0, 0, 0);

        int g0 = batch[rbase], g15 = batch[rbase + 15];
        if (g0 != curg) { FLUSH(curg); curg = g0; }
        if (g0 == g15) {
            // uniform tile: accumulate rows into register partials (+b4 once per row)
            #pragma unroll
            for (int cb = 0; cb < 8; ++cb)
                pacc[cb] += acc[cb][0] + acc[cb][1] + acc[cb][2] + acc[cb][3]
                            + 4.0f * b4r[cb];
        } else {
            // mixed tile (rare): flush pending, then per-row atomics
            FLUSH(curg);
            #pragma unroll
            for (int i = 0; i < 4; ++i) {
                int gi = batch[rbase + lg * 4 + i];
                #pragma unroll
                for (int cb = 0; cb < 8; ++cb)
                    unsafeAtomicAdd(&pooled[gi * 128 + cb * 16 + lm],
                                    acc[cb][i] + b4r[cb]);
            }
            curg = g15;
        }
    }
    FLUSH(curg);
#undef FLUSH
}

// ================= head =================
__global__ void head_kernel(
    const float* __restrict__ pooled, const int* __restrict__ batch,
    const float* __restrict__ Wfc, const float* __restrict__ bfc,
    float* __restrict__ out)
{
    int g = threadIdx.x;
    if (g >= NUM_GRAPHS) return;

    int lo = 0, hi = N_NODES;
    while (lo < hi) { int mid = (lo + hi) >> 1; if (batch[mid] < g) lo = mid + 1; else hi = mid; }
    int beg = lo;
    lo = 0; hi = N_NODES;
    while (lo < hi) { int mid = (lo + hi) >> 1; if (batch[mid] < g + 1) lo = mid + 1; else hi = mid; }
    int cnt = lo - beg;
    float inv = 1.0f / fmaxf((float)cnt, 1.0f);

    float logits[10];
    for (int o = 0; o < 10; ++o) {
        float acc = 0.0f;
        for (int k = 0; k < 128; ++k)
            acc = fmaf(pooled[g * 128 + k], Wfc[k * 10 + o], acc);
        logits[o] = acc * inv + bfc[o];
    }
    float m = -INFINITY;
    for (int o = 0; o < 10; ++o) m = fmaxf(m, logits[o]);
    float s = 0.0f;
    for (int o = 0; o < 10; ++o) s += expf(logits[o] - m);
    float ls = logf(s);
    for (int o = 0; o < 10; ++o) out[g * 10 + o] = logits[o] - m - ls;
}

extern "C" void kernel_launch(void* const* d_in, const int* in_sizes, int n_in,
                              void* d_out, int out_size, void* d_ws, size_t ws_size,
                              hipStream_t stream)
{
    const float* x     = (const float*)d_in[0];
    const int*   ei    = (const int*)d_in[1];
    const int*   src   = ei;
    const int*   dst   = ei + N_EDGES;
    const int*   batch = (const int*)d_in[2];
    const float* W1  = (const float*)d_in[3];
    const float* b1  = (const float*)d_in[4];
    const float* W2  = (const float*)d_in[5];
    const float* b2  = (const float*)d_in[6];
    const float* W3  = (const float*)d_in[7];
    const float* b3  = (const float*)d_in[8];
    const float* W4  = (const float*)d_in[9];
    const float* b4  = (const float*)d_in[10];
    const float* Wfc = (const float*)d_in[11];
    const float* bfc = (const float*)d_in[12];
    float* out = (float*)d_out;

    char* ws = (char*)d_ws;
    ushort* bufA  = (ushort*)(ws);                 // 12.8 MB
    ushort* bufB  = (ushort*)(ws + 12800000);      // 12.8 MB
    int* esrc     = (int*)(ws + 25600000);         // 6.4 MB
    int* rank     = (int*)(ws + 32000000);         // 6.4 MB
    int* rowptr   = (int*)(ws + 38400000);         // 400004 B
    int* deg      = (int*)(ws + 38800016);         // 400000 B
    int* bsum     = (int*)(ws + 39200016);         // 512 B
    float* pooled = (float*)(ws + 39200528);       // 32 KB

    // ---- CSR build ----
    hipMemsetAsync(deg, 0, N_NODES * 4, stream);
    hipMemsetAsync(pooled, 0, NUM_GRAPHS * 128 * 4, stream);
    hist_rank_kernel<<<(N_EDGES + 255) / 256, 256, 0, stream>>>(dst, deg, rank);
    scan_pass1<<<N_SBLK, 256, 0, stream>>>(deg, bsum);
    scan_pass2<<<1, 64, 0, stream>>>(bsum);
    scan_pass3<<<N_SBLK, 256, 0, stream>>>(deg, bsum, rowptr);
    place_kernel<<<(N_EDGES + 255) / 256, 256, 0, stream>>>(src, dst, rank, rowptr, esrc);

    // ---- layer 1 ----
    gemm1_mfma<<<(N_NODES / 16 + 3) / 4, 256, 0, stream>>>(x, W1, bufA);
    agg_bf16<<<N_NODES / 4, 256, 0, stream>>>((const uint*)bufA, (uint*)bufB, rowptr, esrc);
    fused_mid<<<(N_NODES / 16 + 3) / 4, 256, 0, stream>>>(bufB, b1, W2, b2, W3, bufA);

    // ---- layer 2 ----
    agg_bf16<<<N_NODES / 4, 256, 0, stream>>>((const uint*)bufA, (uint*)bufB, rowptr, esrc);
    {
        const int NT = N_NODES / 16;   // 6250
        const int TPW = 4;
        int blocks = (NT + 4 * TPW - 1) / (4 * TPW);   // 391
        k4_mfma_pool<<<blocks, 256, 0, stream>>>(bufB, b3, W4, b4, batch, pooled);
    }

    head_kernel<<<1, 64, 0, stream>>>(pooled, batch, Wfc, bfc, out);
}

// Round 5
// 259.429 us; speedup vs baseline: 16.8225x; 1.1965x over previous
//
#include <hip/hip_runtime.h>
#include <cmath>

#define N_NODES    100000
#define N_EDGES    1600000
#define NUM_GRAPHS 64

// counting-sort geometry
#define BUCK_W     512                               // nodes per coarse bucket
#define NBUCK      196                               // ceil(100000/512)
#define EPB        4096                              // edges per partition block
#define NB1        391                               // ceil(1600000/4096)

typedef __attribute__((ext_vector_type(8))) short bf16x8;
typedef __attribute__((ext_vector_type(4))) float f32x4;

__device__ __forceinline__ ushort f2bf(float x) {
    union { float f; uint u; } v; v.f = x;
    uint r = v.u + 0x7fffu + ((v.u >> 16) & 1u);
    return (ushort)(r >> 16);
}
__device__ __forceinline__ float bf2f(ushort u) {
    union { uint u; float f; } v; v.u = ((uint)u) << 16;
    return v.f;
}

// ========== K1: coarse histogram (blocks [0,NB1)) + gemm1 (rest) ==========
// P1 part: bcount[blk][bin] = #edges of block blk landing in coarse bucket bin.
// gemm1 part: y = x @ W1 (f32 in, bf16 out, MFMA), tile = 16 rows per wave.
__global__ __launch_bounds__(256) void k1_hist_gemm(
    const int* __restrict__ dst, int* __restrict__ bcount,
    const float* __restrict__ x, const float* __restrict__ W1,
    ushort* __restrict__ y)
{
    if (blockIdx.x < NB1) {
        // ---- P1: LDS coarse histogram ----
        __shared__ int shist[NBUCK];
        int tid = threadIdx.x;
        for (int i = tid; i < NBUCK; i += 256) shist[i] = 0;
        __syncthreads();
        int e0 = blockIdx.x * EPB + tid;
        #pragma unroll
        for (int k = 0; k < EPB / 256; ++k) {
            int e = e0 + k * 256;
            if (e < N_EDGES) atomicAdd(&shist[dst[e] >> 9], 1);
        }
        __syncthreads();
        for (int i = tid; i < NBUCK; i += 256)
            bcount[blockIdx.x * NBUCK + i] = shist[i];
        return;
    }
    // ---- gemm1 ----
    int bid = blockIdx.x - NB1;
    int lane = threadIdx.x & 63, wave = threadIdx.x >> 6;
    int lg = lane >> 4, lm = lane & 15;

    bf16x8 Bf[4][4];
    #pragma unroll
    for (int kc = 0; kc < 4; ++kc)
        #pragma unroll
        for (int cb = 0; cb < 4; ++cb) {
            bf16x8 t;
            #pragma unroll
            for (int i = 0; i < 8; ++i)
                t[i] = (short)f2bf(W1[(kc * 32 + lg * 8 + i) * 64 + cb * 16 + lm]);
            Bf[kc][cb] = t;
        }

    const int ntiles = N_NODES / 16;   // 6250
    int tile = bid * 4 + wave;
    if (tile >= ntiles) return;

    int r = tile * 16 + lm;
    f32x4 acc[4] = {};
    #pragma unroll
    for (int kc = 0; kc < 4; ++kc) {
        const float* p = x + (size_t)r * 128 + kc * 32 + lg * 8;
        float4 a0 = *(const float4*)p;
        float4 a1 = *(const float4*)(p + 4);
        bf16x8 af;
        af[0] = (short)f2bf(a0.x); af[1] = (short)f2bf(a0.y);
        af[2] = (short)f2bf(a0.z); af[3] = (short)f2bf(a0.w);
        af[4] = (short)f2bf(a1.x); af[5] = (short)f2bf(a1.y);
        af[6] = (short)f2bf(a1.z); af[7] = (short)f2bf(a1.w);
        #pragma unroll
        for (int cb = 0; cb < 4; ++cb)
            acc[cb] = __builtin_amdgcn_mfma_f32_16x16x32_bf16(af, Bf[kc][cb], acc[cb], 0, 0, 0);
    }
    #pragma unroll
    for (int cb = 0; cb < 4; ++cb)
        #pragma unroll
        for (int i = 0; i < 4; ++i)
            y[(size_t)(tile * 16 + lg * 4 + i) * 64 + cb * 16 + lm] = f2bf(acc[cb][i]);
}

// ========== P2a: per-bucket exclusive scan over blocks ==========
// basetab[bin][blk] = sum_{blk'<blk} bcount[blk'][bin];  btot[bin] = total
__global__ __launch_bounds__(256) void p2a_scan(
    const int* __restrict__ bcount, int* __restrict__ basetab,
    int* __restrict__ btot)
{
    __shared__ int vals[NB1];
    int b = blockIdx.x;          // bucket
    int tid = threadIdx.x;
    for (int j = tid; j < NB1; j += 256)
        vals[j] = bcount[(size_t)j * NBUCK + b];
    __syncthreads();
    if (tid == 0) {
        int run = 0;
        for (int j = 0; j < NB1; ++j) { int t = vals[j]; vals[j] = run; run += t; }
        btot[b] = run;
    }
    __syncthreads();
    for (int j = tid; j < NB1; j += 256)
        basetab[(size_t)b * NB1 + j] = vals[j];
}

// ========== P2b: exclusive scan of bucket totals -> gbase ==========
__global__ void p2b_scan(const int* __restrict__ btot, int* __restrict__ gbase)
{
    __shared__ int v[NBUCK];
    int tid = threadIdx.x;
    for (int j = tid; j < NBUCK; j += 256) v[j] = btot[j];
    __syncthreads();
    if (tid == 0) {
        int run = 0;
        for (int j = 0; j < NBUCK; ++j) { int t = v[j]; v[j] = run; run += t; }
        gbase[NBUCK] = run;   // == N_EDGES
    }
    __syncthreads();
    for (int j = tid; j < NBUCK; j += 256) gbase[j] = v[j];
}

// ========== P3: partition edges into bucket-major packed array ==========
// epack[pos] = (dst&511)<<17 | src  (26 bits)
__global__ __launch_bounds__(256) void p3_partition(
    const int* __restrict__ src, const int* __restrict__ dst,
    const int* __restrict__ basetab, const int* __restrict__ gbase,
    uint* __restrict__ epack)
{
    __shared__ int cur[NBUCK];
    int blk = blockIdx.x, tid = threadIdx.x;
    for (int i = tid; i < NBUCK; i += 256)
        cur[i] = basetab[(size_t)i * NB1 + blk] + gbase[i];
    __syncthreads();
    int e0 = blk * EPB + tid;
    #pragma unroll
    for (int k = 0; k < EPB / 256; ++k) {
        int e = e0 + k * 256;
        if (e < N_EDGES) {
            int d = dst[e], s = src[e];
            int bin = d >> 9;
            int pos = atomicAdd(&cur[bin], 1);
            epack[pos] = ((uint)(d & 511) << 17) | (uint)s;
        }
    }
}

// ========== P4: per-bucket fine CSR (rowptr + esrc), all LDS ==========
__global__ __launch_bounds__(256) void p4_fine(
    const uint* __restrict__ epack, const int* __restrict__ gbase,
    int* __restrict__ rowptr, int* __restrict__ esrc)
{
    __shared__ int hist[BUCK_W];
    int b = blockIdx.x, tid = threadIdx.x;
    int beg = gbase[b], end = gbase[b + 1];
    for (int i = tid; i < BUCK_W; i += 256) hist[i] = 0;
    __syncthreads();
    for (int e = beg + tid; e < end; e += 256)
        atomicAdd(&hist[epack[e] >> 17], 1);
    __syncthreads();
    if (tid == 0) {
        int run = 0;
        for (int i = 0; i < BUCK_W; ++i) { int t = hist[i]; hist[i] = run; run += t; }
    }
    __syncthreads();
    // rowptr (exclusive prefix, global offset)
    for (int i = tid; i < BUCK_W; i += 256) {
        int n = b * BUCK_W + i;
        if (n < N_NODES) rowptr[n] = beg + hist[i];
    }
    if (b == NBUCK - 1 && tid == 0) rowptr[N_NODES] = end;
    __syncthreads();
    // place (hist now serves as cursor)
    for (int e = beg + tid; e < end; e += 256) {
        uint v = epack[e];
        int slot = beg + atomicAdd(&hist[v >> 17], 1);
        esrc[slot] = (int)(v & 0x1FFFFu);
    }
}

// ============== gather (bf16, f32 accum), 2-edge ILP per half-wave ==============
__global__ __launch_bounds__(256) void agg_bf16(
    const uint* __restrict__ in, uint* __restrict__ out,
    const int* __restrict__ rowptr, const int* __restrict__ esrc)
{
    int wave = threadIdx.x >> 6, lane = threadIdx.x & 63;
    int node = blockIdx.x * 4 + wave;
    if (node >= N_NODES) return;
    int h = lane >> 5, c = lane & 31;

    float alo = 0.0f, ahi = 0.0f;
    if (h == 0) {
        uint self = in[(size_t)node * 32 + c];
        alo = bf2f((ushort)(self & 0xffffu));
        ahi = bf2f((ushort)(self >> 16));
    }
    int beg = rowptr[node], end = rowptr[node + 1];
    int e = beg + h;
    for (; e + 2 < end; e += 4) {
        int i0 = esrc[e], i1 = esrc[e + 2];
        uint v0 = in[(size_t)i0 * 32 + c];
        uint v1 = in[(size_t)i1 * 32 + c];
        alo += bf2f((ushort)(v0 & 0xffffu)) + bf2f((ushort)(v1 & 0xffffu));
        ahi += bf2f((ushort)(v0 >> 16))     + bf2f((ushort)(v1 >> 16));
    }
    for (; e < end; e += 2) {
        uint v = in[(size_t)esrc[e] * 32 + c];
        alo += bf2f((ushort)(v & 0xffffu));
        ahi += bf2f((ushort)(v >> 16));
    }
    alo += __shfl_xor(alo, 32, 64);
    ahi += __shfl_xor(ahi, 32, 64);
    if (h == 0)
        out[(size_t)node * 32 + c] = (uint)f2bf(alo) | ((uint)f2bf(ahi) << 16);
}

// ===== fused_mid: t=relu(yagg+b1); h1=relu(t@W2+b2); z=h1@W3 (bf16 MFMA) =====
__global__ __launch_bounds__(256) void fused_mid(
    const ushort* __restrict__ yagg, const float* __restrict__ b1,
    const float* __restrict__ W2, const float* __restrict__ b2,
    const float* __restrict__ W3, ushort* __restrict__ z)
{
    __shared__ __align__(16) float trs[4][16 * 68];
    int lane = threadIdx.x & 63, wave = threadIdx.x >> 6;
    int lg = lane >> 4, lm = lane & 15;

    bf16x8 B2[2][4], B3[2][4];
    #pragma unroll
    for (int kc = 0; kc < 2; ++kc)
        #pragma unroll
        for (int cb = 0; cb < 4; ++cb) {
            bf16x8 t2, t3;
            #pragma unroll
            for (int i = 0; i < 8; ++i) {
                int k = kc * 32 + lg * 8 + i;
                int cc = cb * 16 + lm;
                t2[i] = (short)f2bf(W2[k * 64 + cc]);
                t3[i] = (short)f2bf(W3[k * 64 + cc]);
            }
            B2[kc][cb] = t2; B3[kc][cb] = t3;
        }
    float b1r[2][8];
    #pragma unroll
    for (int kc = 0; kc < 2; ++kc)
        #pragma unroll
        for (int i = 0; i < 8; ++i)
            b1r[kc][i] = b1[kc * 32 + lg * 8 + i];
    float b2r[4];
    #pragma unroll
    for (int cb = 0; cb < 4; ++cb) b2r[cb] = b2[cb * 16 + lm];

    const int ntiles = N_NODES / 16;
    int tile = blockIdx.x * 4 + wave;
    if (tile >= ntiles) return;

    int r = tile * 16 + lm;
    bf16x8 A1[2];
    #pragma unroll
    for (int kc = 0; kc < 2; ++kc) {
        uint4 raw = *(const uint4*)(yagg + (size_t)r * 64 + kc * 32 + lg * 8);
        uint w[4] = {raw.x, raw.y, raw.z, raw.w};
        bf16x8 t;
        #pragma unroll
        for (int j = 0; j < 4; ++j) {
            float flo = bf2f((ushort)(w[j] & 0xffffu)) + b1r[kc][2 * j];
            float fhi = bf2f((ushort)(w[j] >> 16)) + b1r[kc][2 * j + 1];
            t[2 * j]     = (short)f2bf(fmaxf(flo, 0.0f));
            t[2 * j + 1] = (short)f2bf(fmaxf(fhi, 0.0f));
        }
        A1[kc] = t;
    }
    f32x4 acc[4] = {};
    #pragma unroll
    for (int kc = 0; kc < 2; ++kc)
        #pragma unroll
        for (int cb = 0; cb < 4; ++cb)
            acc[cb] = __builtin_amdgcn_mfma_f32_16x16x32_bf16(A1[kc], B2[kc][cb], acc[cb], 0, 0, 0);
    #pragma unroll
    for (int cb = 0; cb < 4; ++cb)
        #pragma unroll
        for (int i = 0; i < 4; ++i)
            trs[wave][(lg * 4 + i) * 68 + cb * 16 + lm] = fmaxf(acc[cb][i] + b2r[cb], 0.0f);
    bf16x8 A2[2];
    #pragma unroll
    for (int kc = 0; kc < 2; ++kc) {
        const float* p = &trs[wave][lm * 68 + kc * 32 + lg * 8];
        float4 u0 = *(const float4*)p;
        float4 u1 = *(const float4*)(p + 4);
        bf16x8 t;
        t[0] = (short)f2bf(u0.x); t[1] = (short)f2bf(u0.y);
        t[2] = (short)f2bf(u0.z); t[3] = (short)f2bf(u0.w);
        t[4] = (short)f2bf(u1.x); t[5] = (short)f2bf(u1.y);
        t[6] = (short)f2bf(u1.z); t[7] = (short)f2bf(u1.w);
        A2[kc] = t;
    }
    f32x4 acc2[4] = {};
    #pragma unroll
    for (int kc = 0; kc < 2; ++kc)
        #pragma unroll
        for (int cb = 0; cb < 4; ++cb)
            acc2[cb] = __builtin_amdgcn_mfma_f32_16x16x32_bf16(A2[kc], B3[kc][cb], acc2[cb], 0, 0, 0);
    #pragma unroll
    for (int cb = 0; cb < 4; ++cb)
        #pragma unroll
        for (int i = 0; i < 4; ++i)
            z[(size_t)(tile * 16 + lg * 4 + i) * 64 + cb * 16 + lm] = f2bf(acc2[cb][i]);
}

// ===== k4 MFMA: o = relu(zagg+b3)@W4+b4 ; pooled[batch[r]] += o =====
__global__ __launch_bounds__(256) void k4_mfma_pool(
    const ushort* __restrict__ zagg, const float* __restrict__ b3,
    const float* __restrict__ W4, const float* __restrict__ b4,
    const int* __restrict__ batch, float* __restrict__ pooled)
{
    int lane = threadIdx.x & 63, wave = threadIdx.x >> 6;
    int lg = lane >> 4, lm = lane & 15;

    bf16x8 B4[2][8];
    #pragma unroll
    for (int kc = 0; kc < 2; ++kc)
        #pragma unroll
        for (int cb = 0; cb < 8; ++cb) {
            bf16x8 t;
            #pragma unroll
            for (int i = 0; i < 8; ++i)
                t[i] = (short)f2bf(W4[(kc * 32 + lg * 8 + i) * 128 + cb * 16 + lm]);
            B4[kc][cb] = t;
        }
    float b3r[2][8];
    #pragma unroll
    for (int kc = 0; kc < 2; ++kc)
        #pragma unroll
        for (int i = 0; i < 8; ++i)
            b3r[kc][i] = b3[kc * 32 + lg * 8 + i];
    float b4r[8];
    #pragma unroll
    for (int cb = 0; cb < 8; ++cb) b4r[cb] = b4[cb * 16 + lm];

    const int NT = N_NODES / 16;   // 6250
    const int TPW = 4;
    int w = blockIdx.x * 4 + wave;
    int t0 = w * TPW;
    if (t0 >= NT) return;
    int t1 = min(t0 + TPW, NT);

    float pacc[8] = {0, 0, 0, 0, 0, 0, 0, 0};
    int curg = batch[t0 * 16];

#define FLUSH(G) do {                                                     \
        _Pragma("unroll")                                                 \
        for (int cb = 0; cb < 8; ++cb) {                                  \
            float v = pacc[cb];                                           \
            v += __shfl_xor(v, 16, 64);                                   \
            v += __shfl_xor(v, 32, 64);                                   \
            if (lane < 16) unsafeAtomicAdd(&pooled[(G) * 128 + cb * 16 + lm], v); \
            pacc[cb] = 0.0f;                                              \
        }                                                                 \
    } while (0)

    for (int t = t0; t < t1; ++t) {
        int rbase = t * 16;
        int r = rbase + lm;
        bf16x8 A[2];
        #pragma unroll
        for (int kc = 0; kc < 2; ++kc) {
            uint4 raw = *(const uint4*)(zagg + (size_t)r * 64 + kc * 32 + lg * 8);
            uint wv[4] = {raw.x, raw.y, raw.z, raw.w};
            bf16x8 tt;
            #pragma unroll
            for (int j = 0; j < 4; ++j) {
                float flo = bf2f((ushort)(wv[j] & 0xffffu)) + b3r[kc][2 * j];
                float fhi = bf2f((ushort)(wv[j] >> 16))    + b3r[kc][2 * j + 1];
                tt[2 * j]     = (short)f2bf(fmaxf(flo, 0.0f));
                tt[2 * j + 1] = (short)f2bf(fmaxf(fhi, 0.0f));
            }
            A[kc] = tt;
        }
        f32x4 acc[8] = {};
        #pragma unroll
        for (int kc = 0; kc < 2; ++kc)
            #pragma unroll
            for (int cb = 0; cb < 8; ++cb)
                acc[cb] = __builtin_amdgcn_mfma_f32_16x16x32_bf16(A[kc], B4[kc][cb], acc[cb], 0, 0, 0);

        int g0 = batch[rbase], g15 = batch[rbase + 15];
        if (g0 != curg) { FLUSH(curg); curg = g0; }
        if (g0 == g15) {
            #pragma unroll
            for (int cb = 0; cb < 8; ++cb)
                pacc[cb] += acc[cb][0] + acc[cb][1] + acc[cb][2] + acc[cb][3]
                            + 4.0f * b4r[cb];
        } else {
            FLUSH(curg);
            #pragma unroll
            for (int i = 0; i < 4; ++i) {
                int gi = batch[rbase + lg * 4 + i];
                #pragma unroll
                for (int cb = 0; cb < 8; ++cb)
                    unsafeAtomicAdd(&pooled[gi * 128 + cb * 16 + lm],
                                    acc[cb][i] + b4r[cb]);
            }
            curg = g15;
        }
    }
    FLUSH(curg);
#undef FLUSH
}

// ================= head =================
__global__ void head_kernel(
    const float* __restrict__ pooled, const int* __restrict__ batch,
    const float* __restrict__ Wfc, const float* __restrict__ bfc,
    float* __restrict__ out)
{
    int g = threadIdx.x;
    if (g >= NUM_GRAPHS) return;

    int lo = 0, hi = N_NODES;
    while (lo < hi) { int mid = (lo + hi) >> 1; if (batch[mid] < g) lo = mid + 1; else hi = mid; }
    int beg = lo;
    lo = 0; hi = N_NODES;
    while (lo < hi) { int mid = (lo + hi) >> 1; if (batch[mid] < g + 1) lo = mid + 1; else hi = mid; }
    int cnt = lo - beg;
    float inv = 1.0f / fmaxf((float)cnt, 1.0f);

    float logits[10];
    for (int o = 0; o < 10; ++o) {
        float acc = 0.0f;
        for (int k = 0; k < 128; ++k)
            acc = fmaf(pooled[g * 128 + k], Wfc[k * 10 + o], acc);
        logits[o] = acc * inv + bfc[o];
    }
    float m = -INFINITY;
    for (int o = 0; o < 10; ++o) m = fmaxf(m, logits[o]);
    float s = 0.0f;
    for (int o = 0; o < 10; ++o) s += expf(logits[o] - m);
    float ls = logf(s);
    for (int o = 0; o < 10; ++o) out[g * 10 + o] = logits[o] - m - ls;
}

extern "C" void kernel_launch(void* const* d_in, const int* in_sizes, int n_in,
                              void* d_out, int out_size, void* d_ws, size_t ws_size,
                              hipStream_t stream)
{
    const float* x     = (const float*)d_in[0];
    const int*   ei    = (const int*)d_in[1];
    const int*   src   = ei;
    const int*   dst   = ei + N_EDGES;
    const int*   batch = (const int*)d_in[2];
    const float* W1  = (const float*)d_in[3];
    const float* b1  = (const float*)d_in[4];
    const float* W2  = (const float*)d_in[5];
    const float* b2  = (const float*)d_in[6];
    const float* W3  = (const float*)d_in[7];
    const float* b3  = (const float*)d_in[8];
    const float* W4  = (const float*)d_in[9];
    const float* b4  = (const float*)d_in[10];
    const float* Wfc = (const float*)d_in[11];
    const float* bfc = (const float*)d_in[12];
    float* out = (float*)d_out;

    char* ws = (char*)d_ws;
    ushort* bufA   = (ushort*)(ws);                 // 12.8 MB
    ushort* bufB   = (ushort*)(ws + 12800000);      // 12.8 MB
    int*  esrc     = (int*) (ws + 25600000);        // 6.4 MB
    uint* epack    = (uint*)(ws + 32000000);        // 6.4 MB
    int*  rowptr   = (int*) (ws + 38400000);        // 400,004 B
    int*  bcount   = (int*) (ws + 38800016);        // 391*196*4 = 306,544 B
    int*  basetab  = (int*) (ws + 39106560);        // 306,544 B
    int*  btot     = (int*) (ws + 39413104);        // 784 B
    int*  gbase    = (int*) (ws + 39413888);        // 788 B
    float* pooled  = (float*)(ws + 39414688);       // 32 KB

    hipMemsetAsync(pooled, 0, NUM_GRAPHS * 128 * 4, stream);

    // ---- K1: coarse hist + gemm1 (independent work, one grid) ----
    {
        int gemm_blocks = (N_NODES / 16 + 3) / 4;   // 1563
        k1_hist_gemm<<<NB1 + gemm_blocks, 256, 0, stream>>>(dst, bcount, x, W1, bufA);
    }
    // ---- CSR build (LDS counting sort, no global atomics) ----
    p2a_scan<<<NBUCK, 256, 0, stream>>>(bcount, basetab, btot);
    p2b_scan<<<1, 256, 0, stream>>>(btot, gbase);
    p3_partition<<<NB1, 256, 0, stream>>>(src, dst, basetab, gbase, epack);
    p4_fine<<<NBUCK, 256, 0, stream>>>(epack, gbase, rowptr, esrc);

    // ---- layer 1 ----
    agg_bf16<<<N_NODES / 4, 256, 0, stream>>>((const uint*)bufA, (uint*)bufB, rowptr, esrc);
    fused_mid<<<(N_NODES / 16 + 3) / 4, 256, 0, stream>>>(bufB, b1, W2, b2, W3, bufA);

    // ---- layer 2 ----
    agg_bf16<<<N_NODES / 4, 256, 0, stream>>>((const uint*)bufA, (uint*)bufB, rowptr, esrc);
    {
        const int NT = N_NODES / 16;   // 6250
        const int TPW = 4;
        int blocks = (NT + 4 * TPW - 1) / (4 * TPW);   // 391
        k4_mfma_pool<<<blocks, 256, 0, stream>>>(bufB, b3, W4, b4, batch, pooled);
    }

    head_kernel<<<1, 64, 0, stream>>>(pooled, batch, Wfc, bfc, out);
}

// Round 6
// 222.698 us; speedup vs baseline: 19.5972x; 1.1649x over previous
//
#include <hip/hip_runtime.h>
#include <cmath>

#define N_NODES    100000
#define N_EDGES    1600000
#define NUM_GRAPHS 64

// counting-sort geometry
#define BUCK_W     512                               // nodes per coarse bucket
#define NBUCK      196                               // ceil(100000/512)
#define EPB        4096                              // edges per partition block
#define NB1        391                               // ceil(1600000/4096)

typedef __attribute__((ext_vector_type(8))) short bf16x8;
typedef __attribute__((ext_vector_type(4))) float f32x4;

__device__ __forceinline__ ushort f2bf(float x) {
    union { float f; uint u; } v; v.f = x;
    uint r = v.u + 0x7fffu + ((v.u >> 16) & 1u);
    return (ushort)(r >> 16);
}
__device__ __forceinline__ float bf2f(ushort u) {
    union { uint u; float f; } v; v.u = ((uint)u) << 16;
    return v.f;
}

// ========== K1: coarse histogram (blocks [0,NB1)) + gemm1 (rest) ==========
__global__ __launch_bounds__(256) void k1_hist_gemm(
    const int* __restrict__ dst, int* __restrict__ bcount,
    const float* __restrict__ x, const float* __restrict__ W1,
    ushort* __restrict__ y)
{
    if (blockIdx.x < NB1) {
        __shared__ int shist[NBUCK];
        int tid = threadIdx.x;
        for (int i = tid; i < NBUCK; i += 256) shist[i] = 0;
        __syncthreads();
        int e0 = blockIdx.x * EPB + tid;
        #pragma unroll
        for (int k = 0; k < EPB / 256; ++k) {
            int e = e0 + k * 256;
            if (e < N_EDGES) atomicAdd(&shist[dst[e] >> 9], 1);
        }
        __syncthreads();
        for (int i = tid; i < NBUCK; i += 256)
            bcount[blockIdx.x * NBUCK + i] = shist[i];
        return;
    }
    int bid = blockIdx.x - NB1;
    int lane = threadIdx.x & 63, wave = threadIdx.x >> 6;
    int lg = lane >> 4, lm = lane & 15;

    bf16x8 Bf[4][4];
    #pragma unroll
    for (int kc = 0; kc < 4; ++kc)
        #pragma unroll
        for (int cb = 0; cb < 4; ++cb) {
            bf16x8 t;
            #pragma unroll
            for (int i = 0; i < 8; ++i)
                t[i] = (short)f2bf(W1[(kc * 32 + lg * 8 + i) * 64 + cb * 16 + lm]);
            Bf[kc][cb] = t;
        }

    const int ntiles = N_NODES / 16;   // 6250
    int tile = bid * 4 + wave;
    if (tile >= ntiles) return;

    int r = tile * 16 + lm;
    f32x4 acc[4] = {};
    #pragma unroll
    for (int kc = 0; kc < 4; ++kc) {
        const float* p = x + (size_t)r * 128 + kc * 32 + lg * 8;
        float4 a0 = *(const float4*)p;
        float4 a1 = *(const float4*)(p + 4);
        bf16x8 af;
        af[0] = (short)f2bf(a0.x); af[1] = (short)f2bf(a0.y);
        af[2] = (short)f2bf(a0.z); af[3] = (short)f2bf(a0.w);
        af[4] = (short)f2bf(a1.x); af[5] = (short)f2bf(a1.y);
        af[6] = (short)f2bf(a1.z); af[7] = (short)f2bf(a1.w);
        #pragma unroll
        for (int cb = 0; cb < 4; ++cb)
            acc[cb] = __builtin_amdgcn_mfma_f32_16x16x32_bf16(af, Bf[kc][cb], acc[cb], 0, 0, 0);
    }
    #pragma unroll
    for (int cb = 0; cb < 4; ++cb)
        #pragma unroll
        for (int i = 0; i < 4; ++i)
            y[(size_t)(tile * 16 + lg * 4 + i) * 64 + cb * 16 + lm] = f2bf(acc[cb][i]);
}

// ========== P2a: per-bucket exclusive scan over blocks ==========
__global__ __launch_bounds__(256) void p2a_scan(
    const int* __restrict__ bcount, int* __restrict__ basetab,
    int* __restrict__ btot)
{
    __shared__ int vals[NB1];
    int b = blockIdx.x;
    int tid = threadIdx.x;
    for (int j = tid; j < NB1; j += 256)
        vals[j] = bcount[(size_t)j * NBUCK + b];
    __syncthreads();
    if (tid == 0) {
        int run = 0;
        for (int j = 0; j < NB1; ++j) { int t = vals[j]; vals[j] = run; run += t; }
        btot[b] = run;
    }
    __syncthreads();
    for (int j = tid; j < NB1; j += 256)
        basetab[(size_t)b * NB1 + j] = vals[j];
}

// ========== P2b: exclusive scan of bucket totals -> gbase ==========
__global__ void p2b_scan(const int* __restrict__ btot, int* __restrict__ gbase)
{
    __shared__ int v[NBUCK];
    int tid = threadIdx.x;
    for (int j = tid; j < NBUCK; j += 256) v[j] = btot[j];
    __syncthreads();
    if (tid == 0) {
        int run = 0;
        for (int j = 0; j < NBUCK; ++j) { int t = v[j]; v[j] = run; run += t; }
        gbase[NBUCK] = run;
    }
    __syncthreads();
    for (int j = tid; j < NBUCK; j += 256) gbase[j] = v[j];
}

// ========== P3: partition edges into bucket-major packed array ==========
__global__ __launch_bounds__(256) void p3_partition(
    const int* __restrict__ src, const int* __restrict__ dst,
    const int* __restrict__ basetab, const int* __restrict__ gbase,
    uint* __restrict__ epack)
{
    __shared__ int cur[NBUCK];
    int blk = blockIdx.x, tid = threadIdx.x;
    for (int i = tid; i < NBUCK; i += 256)
        cur[i] = basetab[(size_t)i * NB1 + blk] + gbase[i];
    __syncthreads();
    int e0 = blk * EPB + tid;
    #pragma unroll
    for (int k = 0; k < EPB / 256; ++k) {
        int e = e0 + k * 256;
        if (e < N_EDGES) {
            int d = dst[e], s = src[e];
            int bin = d >> 9;
            int pos = atomicAdd(&cur[bin], 1);
            epack[pos] = ((uint)(d & 511) << 17) | (uint)s;
        }
    }
}

// ========== P4: per-bucket fine CSR (rowptr + esrc), all LDS ==========
__global__ __launch_bounds__(256) void p4_fine(
    const uint* __restrict__ epack, const int* __restrict__ gbase,
    int* __restrict__ rowptr, int* __restrict__ esrc)
{
    __shared__ int hist[BUCK_W];
    int b = blockIdx.x, tid = threadIdx.x;
    int beg = gbase[b], end = gbase[b + 1];
    for (int i = tid; i < BUCK_W; i += 256) hist[i] = 0;
    __syncthreads();
    for (int e = beg + tid; e < end; e += 256)
        atomicAdd(&hist[epack[e] >> 17], 1);
    __syncthreads();
    if (tid == 0) {
        int run = 0;
        for (int i = 0; i < BUCK_W; ++i) { int t = hist[i]; hist[i] = run; run += t; }
    }
    __syncthreads();
    for (int i = tid; i < BUCK_W; i += 256) {
        int n = b * BUCK_W + i;
        if (n < N_NODES) rowptr[n] = beg + hist[i];
    }
    if (b == NBUCK - 1 && tid == 0) rowptr[N_NODES] = end;
    __syncthreads();
    for (int e = beg + tid; e < end; e += 256) {
        uint v = epack[e];
        int slot = beg + atomicAdd(&hist[v >> 17], 1);
        esrc[slot] = (int)(v & 0x1FFFFu);
    }
}

// ====== gather v2: 8-lane groups, uint4 row loads, 8 edges/wave in flight ======
// lane = grp*8 + sub; grp handles edges e = beg+grp, +8, ...; sub covers 16B of row.
// per-lane acc[8] f32 (channels sub*8 .. sub*8+7); cross-grp shfl reduce at end.
__global__ __launch_bounds__(256) void agg_bf16_v2(
    const uint4* __restrict__ in4, uint4* __restrict__ out4,
    const int* __restrict__ rowptr, const int* __restrict__ esrc)
{
    int wave = threadIdx.x >> 6, lane = threadIdx.x & 63;
    int node = blockIdx.x * 4 + wave;
    if (node >= N_NODES) return;
    int grp = lane >> 3, sub = lane & 7;

    float a[8] = {0, 0, 0, 0, 0, 0, 0, 0};

#define ACCUM(V) do {                                                   \
        uint _w[4] = {(V).x, (V).y, (V).z, (V).w};                      \
        _Pragma("unroll")                                               \
        for (int j = 0; j < 4; ++j) {                                   \
            a[2 * j]     += bf2f((ushort)(_w[j] & 0xffffu));            \
            a[2 * j + 1] += bf2f((ushort)(_w[j] >> 16));                \
        }                                                               \
    } while (0)

    // self term: group 0 only (summed once after cross-group reduce)
    if (grp == 0) {
        uint4 v = in4[(size_t)node * 8 + sub];
        ACCUM(v);
    }

    int beg = rowptr[node], end = rowptr[node + 1];
    int e = beg + grp;
    for (; e + 8 < end; e += 16) {
        int s0 = esrc[e], s1 = esrc[e + 8];
        uint4 v0 = in4[(size_t)s0 * 8 + sub];
        uint4 v1 = in4[(size_t)s1 * 8 + sub];
        ACCUM(v0);
        ACCUM(v1);
    }
    if (e < end) {
        int s = esrc[e];
        uint4 v = in4[(size_t)s * 8 + sub];
        ACCUM(v);
    }
#undef ACCUM

    // reduce across the 8 groups (lanes sharing `sub`)
    #pragma unroll
    for (int m = 8; m < 64; m <<= 1) {
        #pragma unroll
        for (int j = 0; j < 8; ++j)
            a[j] += __shfl_xor(a[j], m, 64);
    }

    if (grp == 0) {
        uint4 o;
        o.x = (uint)f2bf(a[0]) | ((uint)f2bf(a[1]) << 16);
        o.y = (uint)f2bf(a[2]) | ((uint)f2bf(a[3]) << 16);
        o.z = (uint)f2bf(a[4]) | ((uint)f2bf(a[5]) << 16);
        o.w = (uint)f2bf(a[6]) | ((uint)f2bf(a[7]) << 16);
        out4[(size_t)node * 8 + sub] = o;
    }
}

// ===== fused_mid: t=relu(yagg+b1); h1=relu(t@W2+b2); z=h1@W3 (bf16 MFMA) =====
__global__ __launch_bounds__(256) void fused_mid(
    const ushort* __restrict__ yagg, const float* __restrict__ b1,
    const float* __restrict__ W2, const float* __restrict__ b2,
    const float* __restrict__ W3, ushort* __restrict__ z)
{
    __shared__ __align__(16) float trs[4][16 * 68];
    int lane = threadIdx.x & 63, wave = threadIdx.x >> 6;
    int lg = lane >> 4, lm = lane & 15;

    bf16x8 B2[2][4], B3[2][4];
    #pragma unroll
    for (int kc = 0; kc < 2; ++kc)
        #pragma unroll
        for (int cb = 0; cb < 4; ++cb) {
            bf16x8 t2, t3;
            #pragma unroll
            for (int i = 0; i < 8; ++i) {
                int k = kc * 32 + lg * 8 + i;
                int cc = cb * 16 + lm;
                t2[i] = (short)f2bf(W2[k * 64 + cc]);
                t3[i] = (short)f2bf(W3[k * 64 + cc]);
            }
            B2[kc][cb] = t2; B3[kc][cb] = t3;
        }
    float b1r[2][8];
    #pragma unroll
    for (int kc = 0; kc < 2; ++kc)
        #pragma unroll
        for (int i = 0; i < 8; ++i)
            b1r[kc][i] = b1[kc * 32 + lg * 8 + i];
    float b2r[4];
    #pragma unroll
    for (int cb = 0; cb < 4; ++cb) b2r[cb] = b2[cb * 16 + lm];

    const int ntiles = N_NODES / 16;
    int tile = blockIdx.x * 4 + wave;
    if (tile >= ntiles) return;

    int r = tile * 16 + lm;
    bf16x8 A1[2];
    #pragma unroll
    for (int kc = 0; kc < 2; ++kc) {
        uint4 raw = *(const uint4*)(yagg + (size_t)r * 64 + kc * 32 + lg * 8);
        uint w[4] = {raw.x, raw.y, raw.z, raw.w};
        bf16x8 t;
        #pragma unroll
        for (int j = 0; j < 4; ++j) {
            float flo = bf2f((ushort)(w[j] & 0xffffu)) + b1r[kc][2 * j];
            float fhi = bf2f((ushort)(w[j] >> 16)) + b1r[kc][2 * j + 1];
            t[2 * j]     = (short)f2bf(fmaxf(flo, 0.0f));
            t[2 * j + 1] = (short)f2bf(fmaxf(fhi, 0.0f));
        }
        A1[kc] = t;
    }
    f32x4 acc[4] = {};
    #pragma unroll
    for (int kc = 0; kc < 2; ++kc)
        #pragma unroll
        for (int cb = 0; cb < 4; ++cb)
            acc[cb] = __builtin_amdgcn_mfma_f32_16x16x32_bf16(A1[kc], B2[kc][cb], acc[cb], 0, 0, 0);
    #pragma unroll
    for (int cb = 0; cb < 4; ++cb)
        #pragma unroll
        for (int i = 0; i < 4; ++i)
            trs[wave][(lg * 4 + i) * 68 + cb * 16 + lm] = fmaxf(acc[cb][i] + b2r[cb], 0.0f);
    bf16x8 A2[2];
    #pragma unroll
    for (int kc = 0; kc < 2; ++kc) {
        const float* p = &trs[wave][lm * 68 + kc * 32 + lg * 8];
        float4 u0 = *(const float4*)p;
        float4 u1 = *(const float4*)(p + 4);
        bf16x8 t;
        t[0] = (short)f2bf(u0.x); t[1] = (short)f2bf(u0.y);
        t[2] = (short)f2bf(u0.z); t[3] = (short)f2bf(u0.w);
        t[4] = (short)f2bf(u1.x); t[5] = (short)f2bf(u1.y);
        t[6] = (short)f2bf(u1.z); t[7] = (short)f2bf(u1.w);
        A2[kc] = t;
    }
    f32x4 acc2[4] = {};
    #pragma unroll
    for (int kc = 0; kc < 2; ++kc)
        #pragma unroll
        for (int cb = 0; cb < 4; ++cb)
            acc2[cb] = __builtin_amdgcn_mfma_f32_16x16x32_bf16(A2[kc], B3[kc][cb], acc2[cb], 0, 0, 0);
    #pragma unroll
    for (int cb = 0; cb < 4; ++cb)
        #pragma unroll
        for (int i = 0; i < 4; ++i)
            z[(size_t)(tile * 16 + lg * 4 + i) * 64 + cb * 16 + lm] = f2bf(acc2[cb][i]);
}

// ===== k4 MFMA: o = relu(zagg+b3)@W4+b4 ; pooled[batch[r]] += o =====
__global__ __launch_bounds__(256) void k4_mfma_pool(
    const ushort* __restrict__ zagg, const float* __restrict__ b3,
    const float* __restrict__ W4, const float* __restrict__ b4,
    const int* __restrict__ batch, float* __restrict__ pooled)
{
    int lane = threadIdx.x & 63, wave = threadIdx.x >> 6;
    int lg = lane >> 4, lm = lane & 15;

    bf16x8 B4[2][8];
    #pragma unroll
    for (int kc = 0; kc < 2; ++kc)
        #pragma unroll
        for (int cb = 0; cb < 8; ++cb) {
            bf16x8 t;
            #pragma unroll
            for (int i = 0; i < 8; ++i)
                t[i] = (short)f2bf(W4[(kc * 32 + lg * 8 + i) * 128 + cb * 16 + lm]);
            B4[kc][cb] = t;
        }
    float b3r[2][8];
    #pragma unroll
    for (int kc = 0; kc < 2; ++kc)
        #pragma unroll
        for (int i = 0; i < 8; ++i)
            b3r[kc][i] = b3[kc * 32 + lg * 8 + i];
    float b4r[8];
    #pragma unroll
    for (int cb = 0; cb < 8; ++cb) b4r[cb] = b4[cb * 16 + lm];

    const int NT = N_NODES / 16;   // 6250
    const int TPW = 4;
    int w = blockIdx.x * 4 + wave;
    int t0 = w * TPW;
    if (t0 >= NT) return;
    int t1 = min(t0 + TPW, NT);

    float pacc[8] = {0, 0, 0, 0, 0, 0, 0, 0};
    int curg = batch[t0 * 16];

#define FLUSH(G) do {                                                     \
        _Pragma("unroll")                                                 \
        for (int cb = 0; cb < 8; ++cb) {                                  \
            float v = pacc[cb];                                           \
            v += __shfl_xor(v, 16, 64);                                   \
            v += __shfl_xor(v, 32, 64);                                   \
            if (lane < 16) unsafeAtomicAdd(&pooled[(G) * 128 + cb * 16 + lm], v); \
            pacc[cb] = 0.0f;                                              \
        }                                                                 \
    } while (0)

    for (int t = t0; t < t1; ++t) {
        int rbase = t * 16;
        int r = rbase + lm;
        bf16x8 A[2];
        #pragma unroll
        for (int kc = 0; kc < 2; ++kc) {
            uint4 raw = *(const uint4*)(zagg + (size_t)r * 64 + kc * 32 + lg * 8);
            uint wv[4] = {raw.x, raw.y, raw.z, raw.w};
            bf16x8 tt;
            #pragma unroll
            for (int j = 0; j < 4; ++j) {
                float flo = bf2f((ushort)(wv[j] & 0xffffu)) + b3r[kc][2 * j];
                float fhi = bf2f((ushort)(wv[j] >> 16))    + b3r[kc][2 * j + 1];
                tt[2 * j]     = (short)f2bf(fmaxf(flo, 0.0f));
                tt[2 * j + 1] = (short)f2bf(fmaxf(fhi, 0.0f));
            }
            A[kc] = tt;
        }
        f32x4 acc[8] = {};
        #pragma unroll
        for (int kc = 0; kc < 2; ++kc)
            #pragma unroll
            for (int cb = 0; cb < 8; ++cb)
                acc[cb] = __builtin_amdgcn_mfma_f32_16x16x32_bf16(A[kc], B4[kc][cb], acc[cb], 0, 0, 0);

        int g0 = batch[rbase], g15 = batch[rbase + 15];
        if (g0 != curg) { FLUSH(curg); curg = g0; }
        if (g0 == g15) {
            #pragma unroll
            for (int cb = 0; cb < 8; ++cb)
                pacc[cb] += acc[cb][0] + acc[cb][1] + acc[cb][2] + acc[cb][3]
                            + 4.0f * b4r[cb];
        } else {
            FLUSH(curg);
            #pragma unroll
            for (int i = 0; i < 4; ++i) {
                int gi = batch[rbase + lg * 4 + i];
                #pragma unroll
                for (int cb = 0; cb < 8; ++cb)
                    unsafeAtomicAdd(&pooled[gi * 128 + cb * 16 + lm],
                                    acc[cb][i] + b4r[cb]);
            }
            curg = g15;
        }
    }
    FLUSH(curg);
#undef FLUSH
}

// ================= head =================
__global__ void head_kernel(
    const float* __restrict__ pooled, const int* __restrict__ batch,
    const float* __restrict__ Wfc, const float* __restrict__ bfc,
    float* __restrict__ out)
{
    int g = threadIdx.x;
    if (g >= NUM_GRAPHS) return;

    int lo = 0, hi = N_NODES;
    while (lo < hi) { int mid = (lo + hi) >> 1; if (batch[mid] < g) lo = mid + 1; else hi = mid; }
    int beg = lo;
    lo = 0; hi = N_NODES;
    while (lo < hi) { int mid = (lo + hi) >> 1; if (batch[mid] < g + 1) lo = mid + 1; else hi = mid; }
    int cnt = lo - beg;
    float inv = 1.0f / fmaxf((float)cnt, 1.0f);

    float logits[10];
    for (int o = 0; o < 10; ++o) {
        float acc = 0.0f;
        for (int k = 0; k < 128; ++k)
            acc = fmaf(pooled[g * 128 + k], Wfc[k * 10 + o], acc);
        logits[o] = acc * inv + bfc[o];
    }
    float m = -INFINITY;
    for (int o = 0; o < 10; ++o) m = fmaxf(m, logits[o]);
    float s = 0.0f;
    for (int o = 0; o < 10; ++o) s += expf(logits[o] - m);
    float ls = logf(s);
    for (int o = 0; o < 10; ++o) out[g * 10 + o] = logits[o] - m - ls;
}

extern "C" void kernel_launch(void* const* d_in, const int* in_sizes, int n_in,
                              void* d_out, int out_size, void* d_ws, size_t ws_size,
                              hipStream_t stream)
{
    const float* x     = (const float*)d_in[0];
    const int*   ei    = (const int*)d_in[1];
    const int*   src   = ei;
    const int*   dst   = ei + N_EDGES;
    const int*   batch = (const int*)d_in[2];
    const float* W1  = (const float*)d_in[3];
    const float* b1  = (const float*)d_in[4];
    const float* W2  = (const float*)d_in[5];
    const float* b2  = (const float*)d_in[6];
    const float* W3  = (const float*)d_in[7];
    const float* b3  = (const float*)d_in[8];
    const float* W4  = (const float*)d_in[9];
    const float* b4  = (const float*)d_in[10];
    const float* Wfc = (const float*)d_in[11];
    const float* bfc = (const float*)d_in[12];
    float* out = (float*)d_out;

    char* ws = (char*)d_ws;
    ushort* bufA   = (ushort*)(ws);                 // 12.8 MB
    ushort* bufB   = (ushort*)(ws + 12800000);      // 12.8 MB
    int*  esrc     = (int*) (ws + 25600000);        // 6.4 MB
    uint* epack    = (uint*)(ws + 32000000);        // 6.4 MB
    int*  rowptr   = (int*) (ws + 38400000);        // 400,004 B
    int*  bcount   = (int*) (ws + 38800016);        // 306,544 B
    int*  basetab  = (int*) (ws + 39106560);        // 306,544 B
    int*  btot     = (int*) (ws + 39413104);        // 784 B
    int*  gbase    = (int*) (ws + 39413888);        // 788 B
    float* pooled  = (float*)(ws + 39414688);       // 32 KB

    hipMemsetAsync(pooled, 0, NUM_GRAPHS * 128 * 4, stream);

    // ---- K1: coarse hist + gemm1 ----
    {
        int gemm_blocks = (N_NODES / 16 + 3) / 4;   // 1563
        k1_hist_gemm<<<NB1 + gemm_blocks, 256, 0, stream>>>(dst, bcount, x, W1, bufA);
    }
    // ---- CSR build ----
    p2a_scan<<<NBUCK, 256, 0, stream>>>(bcount, basetab, btot);
    p2b_scan<<<1, 256, 0, stream>>>(btot, gbase);
    p3_partition<<<NB1, 256, 0, stream>>>(src, dst, basetab, gbase, epack);
    p4_fine<<<NBUCK, 256, 0, stream>>>(epack, gbase, rowptr, esrc);

    // ---- layer 1 ----
    agg_bf16_v2<<<(N_NODES + 3) / 4, 256, 0, stream>>>(
        (const uint4*)bufA, (uint4*)bufB, rowptr, esrc);
    fused_mid<<<(N_NODES / 16 + 3) / 4, 256, 0, stream>>>(bufB, b1, W2, b2, W3, bufA);

    // ---- layer 2 ----
    agg_bf16_v2<<<(N_NODES + 3) / 4, 256, 0, stream>>>(
        (const uint4*)bufA, (uint4*)bufB, rowptr, esrc);
    {
        const int NT = N_NODES / 16;   // 6250
        const int TPW = 4;
        int blocks = (NT + 4 * TPW - 1) / (4 * TPW);   // 391
        k4_mfma_pool<<<blocks, 256, 0, stream>>>(bufB, b3, W4, b4, batch, pooled);
    }

    head_kernel<<<1, 64, 0, stream>>>(pooled, batch, Wfc, bfc, out);
}

// Round 7
// 216.421 us; speedup vs baseline: 20.1656x; 1.0290x over previous
//
#include <hip/hip_runtime.h>
#include <cmath>

#define N_NODES    100000
#define N_EDGES    1600000
#define NUM_GRAPHS 64

// counting-sort geometry
#define BUCK_W     512                               // nodes per coarse bucket
#define NBUCK      196                               // ceil(100000/512)
#define EPB        4096                              // edges per partition block
#define NB1        391                               // ceil(1600000/4096)
#define GEMM_GS    782                               // grid-stride blocks for gemm1/fused_mid

typedef __attribute__((ext_vector_type(8))) short bf16x8;
typedef __attribute__((ext_vector_type(4))) float f32x4;

__device__ __forceinline__ ushort f2bf(float x) {
    union { float f; uint u; } v; v.f = x;
    uint r = v.u + 0x7fffu + ((v.u >> 16) & 1u);
    return (ushort)(r >> 16);
}
__device__ __forceinline__ float bf2f(ushort u) {
    union { uint u; float f; } v; v.u = ((uint)u) << 16;
    return v.f;
}

// ========== K1: coarse histogram (blocks [0,NB1)) + gemm1 grid-stride (rest) ==========
__global__ __launch_bounds__(256) void k1_hist_gemm(
    const int* __restrict__ dst, int* __restrict__ bcount,
    const float* __restrict__ x, const float* __restrict__ W1,
    ushort* __restrict__ y)
{
    if (blockIdx.x < NB1) {
        __shared__ int shist[NBUCK];
        int tid = threadIdx.x;
        for (int i = tid; i < NBUCK; i += 256) shist[i] = 0;
        __syncthreads();
        int e0 = blockIdx.x * EPB + tid;
        #pragma unroll
        for (int k = 0; k < EPB / 256; ++k) {
            int e = e0 + k * 256;
            if (e < N_EDGES) atomicAdd(&shist[dst[e] >> 9], 1);
        }
        __syncthreads();
        for (int i = tid; i < NBUCK; i += 256)
            bcount[blockIdx.x * NBUCK + i] = shist[i];
        return;
    }
    int bid = blockIdx.x - NB1;
    int lane = threadIdx.x & 63, wave = threadIdx.x >> 6;
    int lg = lane >> 4, lm = lane & 15;

    bf16x8 Bf[4][4];
    #pragma unroll
    for (int kc = 0; kc < 4; ++kc)
        #pragma unroll
        for (int cb = 0; cb < 4; ++cb) {
            bf16x8 t;
            #pragma unroll
            for (int i = 0; i < 8; ++i)
                t[i] = (short)f2bf(W1[(kc * 32 + lg * 8 + i) * 64 + cb * 16 + lm]);
            Bf[kc][cb] = t;
        }

    const int ntiles = N_NODES / 16;   // 6250
    for (int tile = bid * 4 + wave; tile < ntiles; tile += GEMM_GS * 4) {
        int r = tile * 16 + lm;
        f32x4 acc[4] = {};
        #pragma unroll
        for (int kc = 0; kc < 4; ++kc) {
            const float* p = x + (size_t)r * 128 + kc * 32 + lg * 8;
            float4 a0 = *(const float4*)p;
            float4 a1 = *(const float4*)(p + 4);
            bf16x8 af;
            af[0] = (short)f2bf(a0.x); af[1] = (short)f2bf(a0.y);
            af[2] = (short)f2bf(a0.z); af[3] = (short)f2bf(a0.w);
            af[4] = (short)f2bf(a1.x); af[5] = (short)f2bf(a1.y);
            af[6] = (short)f2bf(a1.z); af[7] = (short)f2bf(a1.w);
            #pragma unroll
            for (int cb = 0; cb < 4; ++cb)
                acc[cb] = __builtin_amdgcn_mfma_f32_16x16x32_bf16(af, Bf[kc][cb], acc[cb], 0, 0, 0);
        }
        #pragma unroll
        for (int cb = 0; cb < 4; ++cb)
            #pragma unroll
            for (int i = 0; i < 4; ++i)
                y[(size_t)(tile * 16 + lg * 4 + i) * 64 + cb * 16 + lm] = f2bf(acc[cb][i]);
    }
}

// ========== P2 fused: per-bucket block-scan + global bucket offsets + pooled zero ==========
// basetab[b][blk] = gbase[b] + sum_{blk'<blk} bcount[blk'][b]   (absolute)
__global__ __launch_bounds__(256) void p2_fused(
    const int* __restrict__ bcount, int* __restrict__ basetab,
    int* __restrict__ gbase, float* __restrict__ pooled)
{
    int b = blockIdx.x, tid = threadIdx.x;
    if (b == 0) {
        for (int i = tid; i < NUM_GRAPHS * 128; i += 256) pooled[i] = 0.0f;
    }
    __shared__ int vals[NB1];
    __shared__ int red[256];
    int pb = 0;
    for (int blk = tid; blk < NB1; blk += 256) {
        const int* row = bcount + (size_t)blk * NBUCK;
        int s = 0;
        for (int bin = 0; bin < b; ++bin) s += row[bin];
        pb += s;
        vals[blk] = row[b];
    }
    red[tid] = pb;
    __syncthreads();
    for (int off = 128; off > 0; off >>= 1) {
        if (tid < off) red[tid] += red[tid + off];
        __syncthreads();
    }
    if (tid == 0) {
        int run = red[0];     // gbase[b]
        gbase[b] = run;
        for (int j = 0; j < NB1; ++j) { int t = vals[j]; vals[j] = run; run += t; }
        if (b == NBUCK - 1) gbase[NBUCK] = run;
    }
    __syncthreads();
    for (int j = tid; j < NB1; j += 256)
        basetab[(size_t)b * NB1 + j] = vals[j];
}

// ========== P3: partition edges into bucket-major packed array ==========
__global__ __launch_bounds__(256) void p3_partition(
    const int* __restrict__ src, const int* __restrict__ dst,
    const int* __restrict__ basetab, uint* __restrict__ epack)
{
    __shared__ int cur[NBUCK];
    int blk = blockIdx.x, tid = threadIdx.x;
    for (int i = tid; i < NBUCK; i += 256)
        cur[i] = basetab[(size_t)i * NB1 + blk];
    __syncthreads();
    int e0 = blk * EPB + tid;
    #pragma unroll
    for (int k = 0; k < EPB / 256; ++k) {
        int e = e0 + k * 256;
        if (e < N_EDGES) {
            int d = dst[e], s = src[e];
            int bin = d >> 9;
            int pos = atomicAdd(&cur[bin], 1);
            epack[pos] = ((uint)(d & 511) << 17) | (uint)s;
        }
    }
}

// ========== P4: per-bucket fine CSR (rowptr + esrc), all LDS ==========
__global__ __launch_bounds__(256) void p4_fine(
    const uint* __restrict__ epack, const int* __restrict__ gbase,
    int* __restrict__ rowptr, int* __restrict__ esrc)
{
    __shared__ int hist[BUCK_W];
    int b = blockIdx.x, tid = threadIdx.x;
    int beg = gbase[b], end = gbase[b + 1];
    for (int i = tid; i < BUCK_W; i += 256) hist[i] = 0;
    __syncthreads();
    for (int e = beg + tid; e < end; e += 256)
        atomicAdd(&hist[epack[e] >> 17], 1);
    __syncthreads();
    if (tid == 0) {
        int run = 0;
        for (int i = 0; i < BUCK_W; ++i) { int t = hist[i]; hist[i] = run; run += t; }
    }
    __syncthreads();
    for (int i = tid; i < BUCK_W; i += 256) {
        int n = b * BUCK_W + i;
        if (n < N_NODES) rowptr[n] = beg + hist[i];
    }
    if (b == NBUCK - 1 && tid == 0) rowptr[N_NODES] = end;
    __syncthreads();
    for (int e = beg + tid; e < end; e += 256) {
        uint v = epack[e];
        int slot = beg + atomicAdd(&hist[v >> 17], 1);
        esrc[slot] = (int)(v & 0x1FFFFu);
    }
}

// ====== gather v3: 8-lane group per NODE, uint4 row loads, no shuffles ======
// tid>>3 = node, tid&7 = 16B slice. 8-wide + 4-wide unrolled gather rounds.
__global__ __launch_bounds__(256) void agg_bf16_v3(
    const uint4* __restrict__ in4, uint4* __restrict__ out4,
    const int* __restrict__ rowptr, const int* __restrict__ esrc)
{
    int tid = blockIdx.x * 256 + threadIdx.x;
    int node = tid >> 3;
    if (node >= N_NODES) return;
    int sub = tid & 7;

    float a[8] = {0, 0, 0, 0, 0, 0, 0, 0};

#define ACCUM(V) do {                                                   \
        uint _w[4] = {(V).x, (V).y, (V).z, (V).w};                      \
        _Pragma("unroll")                                               \
        for (int j = 0; j < 4; ++j) {                                   \
            a[2 * j]     += bf2f((ushort)(_w[j] & 0xffffu));            \
            a[2 * j + 1] += bf2f((ushort)(_w[j] >> 16));                \
        }                                                               \
    } while (0)

    // self term
    {
        uint4 v = in4[(size_t)node * 8 + sub];
        ACCUM(v);
    }
    int e = rowptr[node], end = rowptr[node + 1];
    for (; e + 8 <= end; e += 8) {
        int i0 = esrc[e],     i1 = esrc[e + 1], i2 = esrc[e + 2], i3 = esrc[e + 3];
        int i4 = esrc[e + 4], i5 = esrc[e + 5], i6 = esrc[e + 6], i7 = esrc[e + 7];
        uint4 v0 = in4[(size_t)i0 * 8 + sub];
        uint4 v1 = in4[(size_t)i1 * 8 + sub];
        uint4 v2 = in4[(size_t)i2 * 8 + sub];
        uint4 v3 = in4[(size_t)i3 * 8 + sub];
        uint4 v4 = in4[(size_t)i4 * 8 + sub];
        uint4 v5 = in4[(size_t)i5 * 8 + sub];
        uint4 v6 = in4[(size_t)i6 * 8 + sub];
        uint4 v7 = in4[(size_t)i7 * 8 + sub];
        ACCUM(v0); ACCUM(v1); ACCUM(v2); ACCUM(v3);
        ACCUM(v4); ACCUM(v5); ACCUM(v6); ACCUM(v7);
    }
    if (e + 4 <= end) {
        int i0 = esrc[e], i1 = esrc[e + 1], i2 = esrc[e + 2], i3 = esrc[e + 3];
        uint4 v0 = in4[(size_t)i0 * 8 + sub];
        uint4 v1 = in4[(size_t)i1 * 8 + sub];
        uint4 v2 = in4[(size_t)i2 * 8 + sub];
        uint4 v3 = in4[(size_t)i3 * 8 + sub];
        ACCUM(v0); ACCUM(v1); ACCUM(v2); ACCUM(v3);
        e += 4;
    }
    for (; e < end; ++e) {
        uint4 v = in4[(size_t)esrc[e] * 8 + sub];
        ACCUM(v);
    }
#undef ACCUM

    uint4 o;
    o.x = (uint)f2bf(a[0]) | ((uint)f2bf(a[1]) << 16);
    o.y = (uint)f2bf(a[2]) | ((uint)f2bf(a[3]) << 16);
    o.z = (uint)f2bf(a[4]) | ((uint)f2bf(a[5]) << 16);
    o.w = (uint)f2bf(a[6]) | ((uint)f2bf(a[7]) << 16);
    out4[(size_t)node * 8 + sub] = o;
}

// ===== fused_mid: t=relu(yagg+b1); h1=relu(t@W2+b2); z=h1@W3 (bf16 MFMA, grid-stride) =====
__global__ __launch_bounds__(256) void fused_mid(
    const ushort* __restrict__ yagg, const float* __restrict__ b1,
    const float* __restrict__ W2, const float* __restrict__ b2,
    const float* __restrict__ W3, ushort* __restrict__ z)
{
    __shared__ __align__(16) float trs[4][16 * 68];
    int lane = threadIdx.x & 63, wave = threadIdx.x >> 6;
    int lg = lane >> 4, lm = lane & 15;

    bf16x8 B2[2][4], B3[2][4];
    #pragma unroll
    for (int kc = 0; kc < 2; ++kc)
        #pragma unroll
        for (int cb = 0; cb < 4; ++cb) {
            bf16x8 t2, t3;
            #pragma unroll
            for (int i = 0; i < 8; ++i) {
                int k = kc * 32 + lg * 8 + i;
                int cc = cb * 16 + lm;
                t2[i] = (short)f2bf(W2[k * 64 + cc]);
                t3[i] = (short)f2bf(W3[k * 64 + cc]);
            }
            B2[kc][cb] = t2; B3[kc][cb] = t3;
        }
    float b1r[2][8];
    #pragma unroll
    for (int kc = 0; kc < 2; ++kc)
        #pragma unroll
        for (int i = 0; i < 8; ++i)
            b1r[kc][i] = b1[kc * 32 + lg * 8 + i];
    float b2r[4];
    #pragma unroll
    for (int cb = 0; cb < 4; ++cb) b2r[cb] = b2[cb * 16 + lm];

    const int ntiles = N_NODES / 16;
    for (int tile = blockIdx.x * 4 + wave; tile < ntiles; tile += GEMM_GS * 4) {
        int r = tile * 16 + lm;
        bf16x8 A1[2];
        #pragma unroll
        for (int kc = 0; kc < 2; ++kc) {
            uint4 raw = *(const uint4*)(yagg + (size_t)r * 64 + kc * 32 + lg * 8);
            uint w[4] = {raw.x, raw.y, raw.z, raw.w};
            bf16x8 t;
            #pragma unroll
            for (int j = 0; j < 4; ++j) {
                float flo = bf2f((ushort)(w[j] & 0xffffu)) + b1r[kc][2 * j];
                float fhi = bf2f((ushort)(w[j] >> 16)) + b1r[kc][2 * j + 1];
                t[2 * j]     = (short)f2bf(fmaxf(flo, 0.0f));
                t[2 * j + 1] = (short)f2bf(fmaxf(fhi, 0.0f));
            }
            A1[kc] = t;
        }
        f32x4 acc[4] = {};
        #pragma unroll
        for (int kc = 0; kc < 2; ++kc)
            #pragma unroll
            for (int cb = 0; cb < 4; ++cb)
                acc[cb] = __builtin_amdgcn_mfma_f32_16x16x32_bf16(A1[kc], B2[kc][cb], acc[cb], 0, 0, 0);
        #pragma unroll
        for (int cb = 0; cb < 4; ++cb)
            #pragma unroll
            for (int i = 0; i < 4; ++i)
                trs[wave][(lg * 4 + i) * 68 + cb * 16 + lm] = fmaxf(acc[cb][i] + b2r[cb], 0.0f);
        bf16x8 A2[2];
        #pragma unroll
        for (int kc = 0; kc < 2; ++kc) {
            const float* p = &trs[wave][lm * 68 + kc * 32 + lg * 8];
            float4 u0 = *(const float4*)p;
            float4 u1 = *(const float4*)(p + 4);
            bf16x8 t;
            t[0] = (short)f2bf(u0.x); t[1] = (short)f2bf(u0.y);
            t[2] = (short)f2bf(u0.z); t[3] = (short)f2bf(u0.w);
            t[4] = (short)f2bf(u1.x); t[5] = (short)f2bf(u1.y);
            t[6] = (short)f2bf(u1.z); t[7] = (short)f2bf(u1.w);
            A2[kc] = t;
        }
        f32x4 acc2[4] = {};
        #pragma unroll
        for (int kc = 0; kc < 2; ++kc)
            #pragma unroll
            for (int cb = 0; cb < 4; ++cb)
                acc2[cb] = __builtin_amdgcn_mfma_f32_16x16x32_bf16(A2[kc], B3[kc][cb], acc2[cb], 0, 0, 0);
        #pragma unroll
        for (int cb = 0; cb < 4; ++cb)
            #pragma unroll
            for (int i = 0; i < 4; ++i)
                z[(size_t)(tile * 16 + lg * 4 + i) * 64 + cb * 16 + lm] = f2bf(acc2[cb][i]);
    }
}

// ===== k4 MFMA: o = relu(zagg+b3)@W4+b4 ; pooled[batch[r]] += o =====
__global__ __launch_bounds__(256) void k4_mfma_pool(
    const ushort* __restrict__ zagg, const float* __restrict__ b3,
    const float* __restrict__ W4, const float* __restrict__ b4,
    const int* __restrict__ batch, float* __restrict__ pooled)
{
    int lane = threadIdx.x & 63, wave = threadIdx.x >> 6;
    int lg = lane >> 4, lm = lane & 15;

    bf16x8 B4[2][8];
    #pragma unroll
    for (int kc = 0; kc < 2; ++kc)
        #pragma unroll
        for (int cb = 0; cb < 8; ++cb) {
            bf16x8 t;
            #pragma unroll
            for (int i = 0; i < 8; ++i)
                t[i] = (short)f2bf(W4[(kc * 32 + lg * 8 + i) * 128 + cb * 16 + lm]);
            B4[kc][cb] = t;
        }
    float b3r[2][8];
    #pragma unroll
    for (int kc = 0; kc < 2; ++kc)
        #pragma unroll
        for (int i = 0; i < 8; ++i)
            b3r[kc][i] = b3[kc * 32 + lg * 8 + i];
    float b4r[8];
    #pragma unroll
    for (int cb = 0; cb < 8; ++cb) b4r[cb] = b4[cb * 16 + lm];

    const int NT = N_NODES / 16;   // 6250
    const int TPW = 4;
    int w = blockIdx.x * 4 + wave;
    int t0 = w * TPW;
    if (t0 >= NT) return;
    int t1 = min(t0 + TPW, NT);

    float pacc[8] = {0, 0, 0, 0, 0, 0, 0, 0};
    int curg = batch[t0 * 16];

#define FLUSH(G) do {                                                     \
        _Pragma("unroll")                                                 \
        for (int cb = 0; cb < 8; ++cb) {                                  \
            float v = pacc[cb];                                           \
            v += __shfl_xor(v, 16, 64);                                   \
            v += __shfl_xor(v, 32, 64);                                   \
            if (lane < 16) unsafeAtomicAdd(&pooled[(G) * 128 + cb * 16 + lm], v); \
            pacc[cb] = 0.0f;                                              \
        }                                                                 \
    } while (0)

    for (int t = t0; t < t1; ++t) {
        int rbase = t * 16;
        int r = rbase + lm;
        bf16x8 A[2];
        #pragma unroll
        for (int kc = 0; kc < 2; ++kc) {
            uint4 raw = *(const uint4*)(zagg + (size_t)r * 64 + kc * 32 + lg * 8);
            uint wv[4] = {raw.x, raw.y, raw.z, raw.w};
            bf16x8 tt;
            #pragma unroll
            for (int j = 0; j < 4; ++j) {
                float flo = bf2f((ushort)(wv[j] & 0xffffu)) + b3r[kc][2 * j];
                float fhi = bf2f((ushort)(wv[j] >> 16))    + b3r[kc][2 * j + 1];
                tt[2 * j]     = (short)f2bf(fmaxf(flo, 0.0f));
                tt[2 * j + 1] = (short)f2bf(fmaxf(fhi, 0.0f));
            }
            A[kc] = tt;
        }
        f32x4 acc[8] = {};
        #pragma unroll
        for (int kc = 0; kc < 2; ++kc)
            #pragma unroll
            for (int cb = 0; cb < 8; ++cb)
                acc[cb] = __builtin_amdgcn_mfma_f32_16x16x32_bf16(A[kc], B4[kc][cb], acc[cb], 0, 0, 0);

        int g0 = batch[rbase], g15 = batch[rbase + 15];
        if (g0 != curg) { FLUSH(curg); curg = g0; }
        if (g0 == g15) {
            #pragma unroll
            for (int cb = 0; cb < 8; ++cb)
                pacc[cb] += acc[cb][0] + acc[cb][1] + acc[cb][2] + acc[cb][3]
                            + 4.0f * b4r[cb];
        } else {
            FLUSH(curg);
            #pragma unroll
            for (int i = 0; i < 4; ++i) {
                int gi = batch[rbase + lg * 4 + i];
                #pragma unroll
                for (int cb = 0; cb < 8; ++cb)
                    unsafeAtomicAdd(&pooled[gi * 128 + cb * 16 + lm],
                                    acc[cb][i] + b4r[cb]);
            }
            curg = g15;
        }
    }
    FLUSH(curg);
#undef FLUSH
}

// ================= head =================
__global__ void head_kernel(
    const float* __restrict__ pooled, const int* __restrict__ batch,
    const float* __restrict__ Wfc, const float* __restrict__ bfc,
    float* __restrict__ out)
{
    int g = threadIdx.x;
    if (g >= NUM_GRAPHS) return;

    int lo = 0, hi = N_NODES;
    while (lo < hi) { int mid = (lo + hi) >> 1; if (batch[mid] < g) lo = mid + 1; else hi = mid; }
    int beg = lo;
    lo = 0; hi = N_NODES;
    while (lo < hi) { int mid = (lo + hi) >> 1; if (batch[mid] < g + 1) lo = mid + 1; else hi = mid; }
    int cnt = lo - beg;
    float inv = 1.0f / fmaxf((float)cnt, 1.0f);

    float logits[10];
    for (int o = 0; o < 10; ++o) {
        float acc = 0.0f;
        for (int k = 0; k < 128; ++k)
            acc = fmaf(pooled[g * 128 + k], Wfc[k * 10 + o], acc);
        logits[o] = acc * inv + bfc[o];
    }
    float m = -INFINITY;
    for (int o = 0; o < 10; ++o) m = fmaxf(m, logits[o]);
    float s = 0.0f;
    for (int o = 0; o < 10; ++o) s += expf(logits[o] - m);
    float ls = logf(s);
    for (int o = 0; o < 10; ++o) out[g * 10 + o] = logits[o] - m - ls;
}

extern "C" void kernel_launch(void* const* d_in, const int* in_sizes, int n_in,
                              void* d_out, int out_size, void* d_ws, size_t ws_size,
                              hipStream_t stream)
{
    const float* x     = (const float*)d_in[0];
    const int*   ei    = (const int*)d_in[1];
    const int*   src   = ei;
    const int*   dst   = ei + N_EDGES;
    const int*   batch = (const int*)d_in[2];
    const float* W1  = (const float*)d_in[3];
    const float* b1  = (const float*)d_in[4];
    const float* W2  = (const float*)d_in[5];
    const float* b2  = (const float*)d_in[6];
    const float* W3  = (const float*)d_in[7];
    const float* b3  = (const float*)d_in[8];
    const float* W4  = (const float*)d_in[9];
    const float* b4  = (const float*)d_in[10];
    const float* Wfc = (const float*)d_in[11];
    const float* bfc = (const float*)d_in[12];
    float* out = (float*)d_out;

    char* ws = (char*)d_ws;
    ushort* bufA   = (ushort*)(ws);                 // 12.8 MB
    ushort* bufB   = (ushort*)(ws + 12800000);      // 12.8 MB
    int*  esrc     = (int*) (ws + 25600000);        // 6.4 MB
    uint* epack    = (uint*)(ws + 32000000);        // 6.4 MB
    int*  rowptr   = (int*) (ws + 38400000);        // 400,004 B
    int*  bcount   = (int*) (ws + 38800016);        // 306,544 B
    int*  basetab  = (int*) (ws + 39106560);        // 306,544 B
    int*  gbase    = (int*) (ws + 39413888);        // 788 B
    float* pooled  = (float*)(ws + 39414688);       // 32 KB

    // ---- K1: coarse hist + gemm1 (grid-stride) ----
    k1_hist_gemm<<<NB1 + GEMM_GS, 256, 0, stream>>>(dst, bcount, x, W1, bufA);
    // ---- CSR build ----
    p2_fused<<<NBUCK, 256, 0, stream>>>(bcount, basetab, gbase, pooled);
    p3_partition<<<NB1, 256, 0, stream>>>(src, dst, basetab, epack);
    p4_fine<<<NBUCK, 256, 0, stream>>>(epack, gbase, rowptr, esrc);

    // ---- layer 1 ----
    agg_bf16_v3<<<(N_NODES * 8) / 256, 256, 0, stream>>>(
        (const uint4*)bufA, (uint4*)bufB, rowptr, esrc);
    fused_mid<<<GEMM_GS, 256, 0, stream>>>(bufB, b1, W2, b2, W3, bufA);

    // ---- layer 2 ----
    agg_bf16_v3<<<(N_NODES * 8) / 256, 256, 0, stream>>>(
        (const uint4*)bufA, (uint4*)bufB, rowptr, esrc);
    {
        const int NT = N_NODES / 16;   // 6250
        const int TPW = 4;
        int blocks = (NT + 4 * TPW - 1) / (4 * TPW);   // 391
        k4_mfma_pool<<<blocks, 256, 0, stream>>>(bufB, b3, W4, b4, batch, pooled);
    }

    head_kernel<<<1, 64, 0, stream>>>(pooled, batch, Wfc, bfc, out);
}